// Round 3
// baseline (2746.951 us; speedup 1.0000x reference)
//
#include <hip/hip_runtime.h>
#include <hip/hip_bf16.h>

typedef __hip_bfloat16 bf16;

#define Bn   16
#define Nn   4096
#define NPn  1024
#define Kn   32
#define CINn 128
#define CGn  131
#define Cn   256
#define Hn   4
#define XPAD 36   // LDS row stride (floats) for transposed x tile

__device__ __forceinline__ float b2f(bf16 x) { return __bfloat162float(x); }
__device__ __forceinline__ bf16  f2b(float x) { return __float2bfloat16(x); }

// Monotonic float->uint (total order incl. negative d2 from cancellation).
__device__ __forceinline__ unsigned f2ord(float f) {
  unsigned u = __float_as_uint(f);
  return u ^ ((u >> 31) ? 0xffffffffu : 0x80000000u);
}

// =====================================================================
// Kernel 1: KNN. d2 via the reference's exact formula/order with forced
// rn ops (no FMA contraction). Key = (ord(d2)<<32)|index.
// =====================================================================
__global__ __launch_bounds__(256) void knn_kernel(const float* __restrict__ xyz,
                                                  const float* __restrict__ newxyz,
                                                  int* __restrict__ idx_out) {
  __shared__ unsigned long long keys[Nn];
  __shared__ unsigned long long wred[4];
  const int bp  = blockIdx.x;
  const int b   = bp >> 10;
  const int tid = threadIdx.x;
  const float qx = newxyz[bp*3 + 0];
  const float qy = newxyz[bp*3 + 1];
  const float qz = newxyz[bp*3 + 2];
  const float sn = __fadd_rn(__fadd_rn(__fmul_rn(qx,qx), __fmul_rn(qy,qy)),
                             __fmul_rn(qz,qz));
  const float* xb = xyz + (size_t)b * Nn * 3;
  for (int n = tid; n < Nn; n += 256) {
    const float xx = xb[n*3 + 0];
    const float xy = xb[n*3 + 1];
    const float xz = xb[n*3 + 2];
    const float sx  = __fadd_rn(__fadd_rn(__fmul_rn(xx,xx), __fmul_rn(xy,xy)),
                                __fmul_rn(xz,xz));
    const float dot = __fadd_rn(__fadd_rn(__fmul_rn(qx,xx), __fmul_rn(qy,xy)),
                                __fmul_rn(qz,xz));
    const float d2 = __fadd_rn(__fsub_rn(sn, __fmul_rn(2.0f, dot)), sx);
    keys[n] = ((unsigned long long)f2ord(d2) << 32) | (unsigned)n;
  }
  __syncthreads();
  const int lane = tid & 63, wv = tid >> 6;
  for (int s = 0; s < Kn; ++s) {
    unsigned long long m = ~0ull;
    for (int i = tid; i < Nn; i += 256) if (keys[i] < m) m = keys[i];
    #pragma unroll
    for (int d = 32; d; d >>= 1) {   // 64-lane butterfly min (u64 as 2x32)
      const unsigned lo = __shfl_xor((unsigned)(m & 0xffffffffu), d, 64);
      const unsigned hi = __shfl_xor((unsigned)(m >> 32), d, 64);
      const unsigned long long o = ((unsigned long long)hi << 32) | lo;
      if (o < m) m = o;
    }
    if (lane == 0) wred[wv] = m;
    __syncthreads();
    unsigned long long best = wred[0];
    if (wred[1] < best) best = wred[1];
    if (wred[2] < best) best = wred[2];
    if (wred[3] < best) best = wred[3];
    const int n = (int)(best & 0xffffffffu);
    if (tid == 0) { idx_out[(size_t)bp*Kn + s] = n; keys[n] = ~0ull; }
    __syncthreads();
  }
}

// =====================================================================
// Kernel 2: fused gather + gf_max + LN1 + qkv + attention.
// One workgroup per (b,p); wave = head, lane = channel-in-head.
// Q/K/V computed in ONE pass over j (3 weight loads + 2 broadcast
// ds_read_b128 + 24 FMA per j); K/V kept per-lane in registers.
// =====================================================================
__global__ __launch_bounds__(256) void fused_attn_kernel(
    const float* __restrict__ xyz, const float* __restrict__ newxyz,
    const float* __restrict__ featin, const float* __restrict__ w_qkv,
    const float* __restrict__ n1g, const float* __restrict__ n1b,
    const int* __restrict__ idx, bf16* __restrict__ attnout,
    bf16* __restrict__ gfmax) {
  __shared__ __align__(16) float sxT[CGn * XPAD];   // sxT[j*XPAD + kk]
  __shared__ float smean[Kn], srstd[Kn];
  __shared__ int sidx[Kn];
  const int bp  = blockIdx.x;
  const int b   = bp >> 10;
  const int tid = threadIdx.x;
  if (tid < Kn) {
    int n = idx[(size_t)bp*Kn + tid];
    sidx[tid] = ((unsigned)n < (unsigned)Nn) ? n : 0;   // defensive clamp
  }
  __syncthreads();
  // gather gf (K-transposed): j<3 relative xyz, else features
  for (int e = tid; e < CGn*Kn; e += 256) {
    const int j = e >> 5, kk = e & 31;
    const int n = sidx[kk];
    float v;
    if (j < 3) v = xyz[((size_t)b*Nn + n)*3 + j] - newxyz[bp*3 + j];
    else       v = featin[((size_t)b*Nn + n)*CINn + (j-3)];
    sxT[j*XPAD + kk] = v;
  }
  __syncthreads();
  // gf_max over K (raw gf, pre-LN) -> bf16 staging (row stride 132)
  if (tid < CGn) {
    float m = -1e30f;
    #pragma unroll
    for (int kk = 0; kk < Kn; ++kk) m = fmaxf(m, sxT[tid*XPAD + kk]);
    gfmax[(size_t)bp*132 + tid] = f2b(m);
  }
  // LN1 stats per neighbor row (over CGn=131 channels)
  if (tid < Kn) {
    float s = 0.f, s2 = 0.f;
    for (int j = 0; j < CGn; ++j) { const float v = sxT[j*XPAD + tid]; s += v; s2 += v*v; }
    const float mean = s * (1.0f/CGn);
    const float var  = s2 * (1.0f/CGn) - mean*mean;
    smean[tid] = mean;
    srstd[tid] = rsqrtf(var + 1e-3f);
  }
  __syncthreads();
  for (int e = tid; e < CGn*Kn; e += 256) {
    const int j = e >> 5, kk = e & 31;
    float v = sxT[j*XPAD + kk];
    sxT[j*XPAD + kk] = (v - smean[kk]) * srstd[kk] * n1g[j] + n1b[j];
  }
  __syncthreads();
  // ---- attention ----
  const int h = tid >> 6, d = tid & 63;
  const int cq = h*64 + d, ck = 256 + cq, cv = 512 + cq;
  float Kreg[Kn], Vreg[Kn];
  float qmax = -1e30f;
  #pragma unroll
  for (int kb = 0; kb < Kn; kb += 8) {
    float aq[8] = {}, ak[8] = {}, av[8] = {};
    for (int j = 0; j < CGn; ++j) {
      const float* wrow = w_qkv + j*768;
      const float wq = wrow[cq], wk = wrow[ck], wv = wrow[cv];
      const float4* xp = (const float4*)(sxT + j*XPAD + kb);
      const float4 x0 = xp[0], x1 = xp[1];
      aq[0]=fmaf(x0.x,wq,aq[0]); aq[1]=fmaf(x0.y,wq,aq[1]);
      aq[2]=fmaf(x0.z,wq,aq[2]); aq[3]=fmaf(x0.w,wq,aq[3]);
      aq[4]=fmaf(x1.x,wq,aq[4]); aq[5]=fmaf(x1.y,wq,aq[5]);
      aq[6]=fmaf(x1.z,wq,aq[6]); aq[7]=fmaf(x1.w,wq,aq[7]);
      ak[0]=fmaf(x0.x,wk,ak[0]); ak[1]=fmaf(x0.y,wk,ak[1]);
      ak[2]=fmaf(x0.z,wk,ak[2]); ak[3]=fmaf(x0.w,wk,ak[3]);
      ak[4]=fmaf(x1.x,wk,ak[4]); ak[5]=fmaf(x1.y,wk,ak[5]);
      ak[6]=fmaf(x1.z,wk,ak[6]); ak[7]=fmaf(x1.w,wk,ak[7]);
      av[0]=fmaf(x0.x,wv,av[0]); av[1]=fmaf(x0.y,wv,av[1]);
      av[2]=fmaf(x0.z,wv,av[2]); av[3]=fmaf(x0.w,wv,av[3]);
      av[4]=fmaf(x1.x,wv,av[4]); av[5]=fmaf(x1.y,wv,av[5]);
      av[6]=fmaf(x1.z,wv,av[6]); av[7]=fmaf(x1.w,wv,av[7]);
    }
    #pragma unroll
    for (int i = 0; i < 8; ++i) {
      qmax = fmaxf(qmax, aq[i]);
      Kreg[kb+i] = ak[i];
      Vreg[kb+i] = av[i];
    }
  }
  // logits[kk] = sum_d qmax[d]*K[kk][d] via 64-lane butterflies
  float mylogit = 0.f;
  #pragma unroll
  for (int kk = 0; kk < Kn; ++kk) {
    float lp = qmax * Kreg[kk];
    #pragma unroll
    for (int dd = 32; dd; dd >>= 1) lp += __shfl_xor(lp, dd, 64);
    if (d == kk) mylogit = lp;   // lane kk keeps logit kk
  }
  // softmax over 32 neighbors within the wave
  float aw;
  {
    const float l = (d < Kn) ? mylogit * 0.0625f : -1e30f;   // * C^-0.5
    float mx = l;
    #pragma unroll
    for (int dd = 32; dd; dd >>= 1) mx = fmaxf(mx, __shfl_xor(mx, dd, 64));
    const float e = (d < Kn) ? expf(l - mx) : 0.f;
    float ssum = e;
    #pragma unroll
    for (int dd = 32; dd; dd >>= 1) ssum += __shfl_xor(ssum, dd, 64);
    aw = e / ssum;
  }
  // out[d] = sum_kk aw[kk]*V[kk][d]
  float out = 0.f;
  #pragma unroll
  for (int kk = 0; kk < Kn; ++kk)
    out = fmaf(__shfl(aw, kk, 64), Vreg[kk], out);
  attnout[(size_t)bp*Cn + cq] = f2b(out);   // cq == tid, coalesced
}

// =====================================================================
// Kernel 3: 64x64-tile GEMM, D = epi(A@W + bias [+S]).
// A bf16 (staged) or via template; W fp32 (Ka x N row-major, from d_in);
// bias/S fp32; D fp32 or bf16. fp32 accumulate.
// =====================================================================
template<bool RELU, bool ADD_S, bool OUT_BF16>
__global__ __launch_bounds__(256) void gemm_kernel(
    const bf16* __restrict__ A, int lda, int Ka,
    const float* __restrict__ W, int N, const float* __restrict__ bias,
    const float* __restrict__ S, void* __restrict__ Dv) {
  __shared__ __align__(16) float As[16][68];   // K-major A tile
  __shared__ __align__(16) float Bs[16][68];
  const int tile_n = blockIdx.x * 64;
  const int tile_m = blockIdx.y * 64;
  const int tid = threadIdx.x;
  const int tx = tid & 15, ty = tid >> 4;
  float acc[4][4] = {};
  const int nk = (Ka + 15) >> 4;
  for (int kb = 0; kb < nk; ++kb) {
    const int k0 = kb * 16;
    #pragma unroll
    for (int e = tid; e < 1024; e += 256) {
      const int k = e & 15, mm = e >> 4;
      const int kk = k0 + k;
      As[k][mm] = (kk < Ka) ? b2f(A[(size_t)(tile_m+mm)*lda + kk]) : 0.f;
    }
    #pragma unroll
    for (int e = tid; e < 1024; e += 256) {
      const int nn = e & 63, k = e >> 6;
      const int kk = k0 + k;
      Bs[k][nn] = (kk < Ka) ? W[(size_t)kk*N + tile_n + nn] : 0.f;
    }
    __syncthreads();
    #pragma unroll
    for (int k = 0; k < 16; ++k) {
      const float4 aq = *(const float4*)&As[k][ty*4];
      const float4 bq = *(const float4*)&Bs[k][tx*4];
      const float av[4] = {aq.x, aq.y, aq.z, aq.w};
      const float bv[4] = {bq.x, bq.y, bq.z, bq.w};
      #pragma unroll
      for (int i = 0; i < 4; ++i)
        #pragma unroll
        for (int j = 0; j < 4; ++j)
          acc[i][j] = fmaf(av[i], bv[j], acc[i][j]);
    }
    __syncthreads();
  }
  #pragma unroll
  for (int i = 0; i < 4; ++i) {
    const int m = tile_m + ty*4 + i;
    #pragma unroll
    for (int j = 0; j < 4; ++j) {
      const int n = tile_n + tx*4 + j;
      float v = acc[i][j] + bias[n];
      if (RELU) v = fmaxf(v, 0.f);
      if (ADD_S) v += S[(size_t)m*N + n];
      if (OUT_BF16) ((bf16*)Dv)[(size_t)m*N + n] = f2b(v);
      else          ((float*)Dv)[(size_t)m*N + n] = v;
    }
  }
}

// =====================================================================
// Kernel 4: LayerNorm2 over C=256, one wave per row; fp32 in, bf16 out.
// =====================================================================
__global__ __launch_bounds__(64) void ln2_kernel(const float* __restrict__ feat,
                                                 const float* __restrict__ g,
                                                 const float* __restrict__ b,
                                                 bf16* __restrict__ out) {
  const int r = blockIdx.x, lane = threadIdx.x;
  const float4 v = *(const float4*)(feat + (size_t)r*Cn + lane*4);
  float s  = v.x + v.y + v.z + v.w;
  float s2 = v.x*v.x + v.y*v.y + v.z*v.z + v.w*v.w;
  #pragma unroll
  for (int d = 32; d; d >>= 1) { s += __shfl_xor(s, d, 64); s2 += __shfl_xor(s2, d, 64); }
  const float mean = s * (1.f/256.f);
  const float var  = s2 * (1.f/256.f) - mean*mean;
  const float rstd = rsqrtf(var + 1e-3f);
  const float vv[4] = {v.x, v.y, v.z, v.w};
  #pragma unroll
  for (int c = 0; c < 4; ++c) {
    const int col = lane*4 + c;
    out[(size_t)r*Cn + col] = f2b((vv[c] - mean)*rstd*g[col] + b[col]);
  }
}

// =====================================================================
// kernel_launch — fp32 in/out. Workspace (40 MiB total, with overlays):
//   featB  fp32 [16384*256] @ 0           16 MiB  live to end (residual)
//   attnA  bf16 [16384*256] @ 16,777,216   8 MiB  attnout -> later ln2out
//   gfmax  bf16 [16384*132] @ 25,165,824   4.33 MiB } dead before fc1;
//   idx    int  [16384*32]  @ 29,491,200   2 MiB   } fc1out overlays them
//   fc1out bf16 [16384*512] @ 25,165,824  16 MiB  (ends 41,943,040)
// =====================================================================
extern "C" void kernel_launch(void* const* d_in, const int* in_sizes, int n_in,
                              void* d_out, int out_size, void* d_ws, size_t ws_size,
                              hipStream_t stream) {
  const float* xyz     = (const float*)d_in[0];
  const float* newxyz  = (const float*)d_in[1];
  const float* featin  = (const float*)d_in[2];
  const float* w_qkv   = (const float*)d_in[3];
  const float* proj_w  = (const float*)d_in[4];
  const float* proj_b  = (const float*)d_in[5];
  const float* dense_w = (const float*)d_in[6];
  const float* dense_b = (const float*)d_in[7];
  const float* fc1_w   = (const float*)d_in[8];
  const float* fc1_b   = (const float*)d_in[9];
  const float* fc2_w   = (const float*)d_in[10];
  const float* fc2_b   = (const float*)d_in[11];
  const float* n1g     = (const float*)d_in[12];
  const float* n1b     = (const float*)d_in[13];
  const float* n2g     = (const float*)d_in[14];
  const float* n2b     = (const float*)d_in[15];

  char*  ws     = (char*)d_ws;
  float* featB  = (float*)(ws + 0);
  bf16*  attnA  = (bf16*)(ws + 16777216);   // attnout, later ln2out
  bf16*  gfmax  = (bf16*)(ws + 25165824);
  int*   idxws  = (int*) (ws + 29491200);
  bf16*  fc1out = (bf16*)(ws + 25165824);   // overlays gfmax+idx (dead)

  const int M = Bn * NPn;  // 16384

  knn_kernel<<<dim3(M), dim3(256), 0, stream>>>(xyz, newxyz, idxws);
  fused_attn_kernel<<<dim3(M), dim3(256), 0, stream>>>(
      xyz, newxyz, featin, w_qkv, n1g, n1b, idxws, attnA, gfmax);
  // featB = relu(attn @ proj_w + proj_b)
  gemm_kernel<true, false, false><<<dim3(Cn/64, M/64), dim3(256), 0, stream>>>(
      attnA, Cn, Cn, proj_w, Cn, proj_b, nullptr, featB);
  // featB += relu(gfmax @ dense_w + dense_b)   (elementwise in-place safe)
  gemm_kernel<true, true, false><<<dim3(Cn/64, M/64), dim3(256), 0, stream>>>(
      gfmax, 132, CGn, dense_w, Cn, dense_b, featB, featB);
  // attnA <- LN2(featB) in bf16 (attnout dead, reuse region)
  ln2_kernel<<<dim3(M), dim3(64), 0, stream>>>(featB, n2g, n2b, attnA);
  // fc1out = relu(attnA @ fc1 + b1)
  gemm_kernel<true, false, true><<<dim3(512/64, M/64), dim3(256), 0, stream>>>(
      attnA, Cn, Cn, fc1_w, 512, fc1_b, nullptr, fc1out);
  // out = fc1out @ fc2 + b2 + featB   (fp32 output)
  gemm_kernel<false, true, false><<<dim3(Cn/64, M/64), dim3(256), 0, stream>>>(
      fc1out, 512, 512, fc2_w, Cn, fc2_b, featB, d_out);
}

// Round 4
// 1683.829 us; speedup vs baseline: 1.6314x; 1.6314x over previous
//
#include <hip/hip_runtime.h>
#include <hip/hip_bf16.h>

typedef __hip_bfloat16 bf16;

#define Bn   16
#define Nn   4096
#define NPn  1024
#define Kn   32
#define CINn 128
#define CGn  131
#define Cn   256
#define Hn   4
#define KPAD 160   // qkv K padded to 5x32
#define XBS  168   // Xb (bf16) row stride: 336 B, 16B-aligned, conflict-benign
#define XFS  132   // Xf (fp32) row stride

typedef __attribute__((ext_vector_type(8))) short frag_ab;   // 8 bf16
typedef __attribute__((ext_vector_type(4))) float frag_cd;   // 4 fp32

__device__ __forceinline__ float b2f(bf16 x) { return __bfloat162float(x); }
__device__ __forceinline__ bf16  f2b(float x) { return __float2bfloat16(x); }
__device__ __forceinline__ short f2bs(float x) {             // bf16 bits as short
  union { bf16 h; short s; } u; u.h = __float2bfloat16(x); return u.s;
}

// Monotonic float->uint (total order incl. negative d2 from cancellation).
__device__ __forceinline__ unsigned f2ord(float f) {
  unsigned u = __float_as_uint(f);
  return u ^ ((u >> 31) ? 0xffffffffu : 0x80000000u);
}

// =====================================================================
// Kernel 1: KNN (unchanged from round 3 — bit-matches np's d2 formula).
// =====================================================================
__global__ __launch_bounds__(256) void knn_kernel(const float* __restrict__ xyz,
                                                  const float* __restrict__ newxyz,
                                                  int* __restrict__ idx_out) {
  __shared__ unsigned long long keys[Nn];
  __shared__ unsigned long long wred[4];
  const int bp  = blockIdx.x;
  const int b   = bp >> 10;
  const int tid = threadIdx.x;
  const float qx = newxyz[bp*3 + 0];
  const float qy = newxyz[bp*3 + 1];
  const float qz = newxyz[bp*3 + 2];
  const float sn = __fadd_rn(__fadd_rn(__fmul_rn(qx,qx), __fmul_rn(qy,qy)),
                             __fmul_rn(qz,qz));
  const float* xb = xyz + (size_t)b * Nn * 3;
  for (int n = tid; n < Nn; n += 256) {
    const float xx = xb[n*3 + 0];
    const float xy = xb[n*3 + 1];
    const float xz = xb[n*3 + 2];
    const float sx  = __fadd_rn(__fadd_rn(__fmul_rn(xx,xx), __fmul_rn(xy,xy)),
                                __fmul_rn(xz,xz));
    const float dot = __fadd_rn(__fadd_rn(__fmul_rn(qx,xx), __fmul_rn(qy,xy)),
                                __fmul_rn(qz,xz));
    const float d2 = __fadd_rn(__fsub_rn(sn, __fmul_rn(2.0f, dot)), sx);
    keys[n] = ((unsigned long long)f2ord(d2) << 32) | (unsigned)n;
  }
  __syncthreads();
  const int lane = tid & 63, wv = tid >> 6;
  for (int s = 0; s < Kn; ++s) {
    unsigned long long m = ~0ull;
    for (int i = tid; i < Nn; i += 256) if (keys[i] < m) m = keys[i];
    #pragma unroll
    for (int d = 32; d; d >>= 1) {
      const unsigned lo = __shfl_xor((unsigned)(m & 0xffffffffu), d, 64);
      const unsigned hi = __shfl_xor((unsigned)(m >> 32), d, 64);
      const unsigned long long o = ((unsigned long long)hi << 32) | lo;
      if (o < m) m = o;
    }
    if (lane == 0) wred[wv] = m;
    __syncthreads();
    unsigned long long best = wred[0];
    if (wred[1] < best) best = wred[1];
    if (wred[2] < best) best = wred[2];
    if (wred[3] < best) best = wred[3];
    const int n = (int)(best & 0xffffffffu);
    if (tid == 0) { idx_out[(size_t)bp*Kn + s] = n; keys[n] = ~0ull; }
    __syncthreads();
  }
}

// =====================================================================
// Kernel 1b: pre-swizzle w_qkv (fp32 131x768) into bf16 B-fragment order
// for mfma_f32_16x16x32_bf16: element (kt,nt,lane,j) = W[kt*32+(lane>>4)*8+j]
// [nt*16+(lane&15)], zero for k>=131. Output flat index = linear thread id.
// 5*48*64*8 = 122880 shorts = 245 KB.
// =====================================================================
__global__ __launch_bounds__(256) void wqkv_prep_kernel(const float* __restrict__ w_qkv,
                                                        short* __restrict__ wfrag) {
  const int t = blockIdx.x * 256 + threadIdx.x;   // grid exactly 480*256
  int idx = t;
  const int j    = idx & 7;   idx >>= 3;
  const int lane = idx & 63;  idx >>= 6;
  const int nt   = idx % 48;
  const int kt   = idx / 48;
  const int k = kt*32 + (lane >> 4)*8 + j;
  const int n = nt*16 + (lane & 15);
  wfrag[t] = (k < CGn) ? f2bs(w_qkv[(size_t)k*768 + n]) : (short)0;
}

// =====================================================================
// Kernel 2: fused gather + gf_max + LN1 + MFMA qkv + attention.
// Block = 1 point (256 thr, 4 waves); wave w = head w.
// qkv: X(32x131 bf16) @ W(131x768 bf16) via 16x16x32 bf16 MFMA,
// B-fragments pre-swizzled in global (L2-resident), A-fragments from LDS.
// Attention reduced fully in-register from the MFMA C-layout.
// =====================================================================
__global__ __launch_bounds__(256) void fused_attn_kernel(
    const float* __restrict__ xyz, const float* __restrict__ newxyz,
    const float* __restrict__ featin, const short* __restrict__ wfrag,
    const float* __restrict__ n1g, const float* __restrict__ n1b,
    const int* __restrict__ idx, bf16* __restrict__ attnout,
    bf16* __restrict__ gfmax) {
  __shared__ float Xf[Kn * XFS];                 // fp32 gather (row-major/neighbor)
  __shared__ __align__(16) short Xb[Kn * XBS];   // bf16 LN'd, MFMA A-layout
  __shared__ float smean[Kn], srstd[Kn];
  __shared__ int sidx[Kn];
  const int bp  = blockIdx.x;
  const int b   = bp >> 10;
  const int tid = threadIdx.x;
  if (tid < Kn) {
    int n = idx[(size_t)bp*Kn + tid];
    sidx[tid] = ((unsigned)n < (unsigned)Nn) ? n : 0;
  }
  __syncthreads();
  // gather: Xf[kk][j], j<131 (3 rel-xyz + 128 feats); coalesced over j
  for (int e = tid; e < Kn*XFS; e += 256) {
    const int kk = e / XFS, j = e % XFS;
    if (j >= CGn) continue;
    const int n = sidx[kk];
    float v;
    if (j < 3) v = xyz[((size_t)b*Nn + n)*3 + j] - newxyz[bp*3 + j];
    else       v = featin[((size_t)b*Nn + n)*CINn + (j-3)];
    Xf[kk*XFS + j] = v;
  }
  __syncthreads();
  // gf_max over K (raw, pre-LN) -> bf16 staging (row stride 132)
  if (tid < CGn) {
    float m = -1e30f;
    #pragma unroll
    for (int kk = 0; kk < Kn; ++kk) m = fmaxf(m, Xf[kk*XFS + tid]);
    gfmax[(size_t)bp*132 + tid] = f2b(m);
  }
  // LN1 stats per neighbor row
  if (tid < Kn) {
    float s = 0.f, s2 = 0.f;
    for (int j = 0; j < CGn; ++j) { const float v = Xf[tid*XFS + j]; s += v; s2 += v*v; }
    const float mean = s * (1.0f/CGn);
    const float var  = s2 * (1.0f/CGn) - mean*mean;
    smean[tid] = mean;
    srstd[tid] = rsqrtf(var + 1e-3f);
  }
  __syncthreads();
  // Xb[kk][j] = bf16(LN(Xf)), zero-pad j in [131,160)
  for (int e = tid; e < Kn*KPAD; e += 256) {
    const int kk = e / KPAD, j = e % KPAD;
    float v = 0.f;
    if (j < CGn)
      v = (Xf[kk*XFS + j] - smean[kk]) * srstd[kk] * n1g[j] + n1b[j];
    Xb[kk*XBS + j] = f2bs(v);
  }
  __syncthreads();
  // ---- MFMA qkv: wave w computes head w's q,k,v (3 x 4 N-tiles x 2 M-tiles)
  const int lane = tid & 63, w = tid >> 6;
  const int col = lane & 15, quad = lane >> 4;
  frag_cd acc[3][4][2] = {};
  for (int kt = 0; kt < 5; ++kt) {
    const int ko = kt*32 + quad*8;
    const frag_ab a0 = *(const frag_ab*)&Xb[ col      *XBS + ko];
    const frag_ab a1 = *(const frag_ab*)&Xb[(16+col)  *XBS + ko];
    #pragma unroll
    for (int part = 0; part < 3; ++part) {
      #pragma unroll
      for (int ntl = 0; ntl < 4; ++ntl) {
        const int nt = part*16 + w*4 + ntl;
        const frag_ab bf = *(const frag_ab*)(wfrag + ((size_t)(kt*48 + nt)*64 + lane)*8);
        acc[part][ntl][0] = __builtin_amdgcn_mfma_f32_16x16x32_bf16(a0, bf, acc[part][ntl][0], 0, 0, 0);
        acc[part][ntl][1] = __builtin_amdgcn_mfma_f32_16x16x32_bf16(a1, bf, acc[part][ntl][1], 0, 0, 0);
      }
    }
  }
  // ---- attention in-register. C-layout: col(n)=lane&15, row(m)=quad*4+reg.
  // Lane holds, per ntl (channel c = ntl*16+col), neighbors kk = mt*16+quad*4+r.
  // qm[c] = max over kk: in-lane over (mt,r), cross-quad via xor 16/32.
  float qm[4];
  #pragma unroll
  for (int ntl = 0; ntl < 4; ++ntl) {
    float m = -1e30f;
    #pragma unroll
    for (int mt = 0; mt < 2; ++mt)
      #pragma unroll
      for (int r = 0; r < 4; ++r) m = fmaxf(m, acc[0][ntl][mt][r]);
    m = fmaxf(m, __shfl_xor(m, 16, 64));
    m = fmaxf(m, __shfl_xor(m, 32, 64));
    qm[ntl] = m;
  }
  // logits[kk] = (sum_c qm[c]*K[kk][c]) * C^-0.5 ; col-sum via xor 1..8
  float lg[2][4];
  #pragma unroll
  for (int mt = 0; mt < 2; ++mt)
    #pragma unroll
    for (int r = 0; r < 4; ++r) {
      float p = 0.f;
      #pragma unroll
      for (int ntl = 0; ntl < 4; ++ntl) p = fmaf(qm[ntl], acc[1][ntl][mt][r], p);
      #pragma unroll
      for (int d = 1; d < 16; d <<= 1) p += __shfl_xor(p, d, 64);
      lg[mt][r] = p * 0.0625f;
    }
  // softmax over the 32 kk (8 in-lane x 4 quads)
  float mx = -1e30f;
  #pragma unroll
  for (int mt = 0; mt < 2; ++mt)
    #pragma unroll
    for (int r = 0; r < 4; ++r) mx = fmaxf(mx, lg[mt][r]);
  mx = fmaxf(mx, __shfl_xor(mx, 16, 64));
  mx = fmaxf(mx, __shfl_xor(mx, 32, 64));
  float aw[2][4], ssum = 0.f;
  #pragma unroll
  for (int mt = 0; mt < 2; ++mt)
    #pragma unroll
    for (int r = 0; r < 4; ++r) { aw[mt][r] = expf(lg[mt][r] - mx); ssum += aw[mt][r]; }
  ssum += __shfl_xor(ssum, 16, 64);
  ssum += __shfl_xor(ssum, 32, 64);
  const float inv = 1.f / ssum;
  // out[c] = sum_kk aw[kk]*V[kk][c]
  #pragma unroll
  for (int ntl = 0; ntl < 4; ++ntl) {
    float o = 0.f;
    #pragma unroll
    for (int mt = 0; mt < 2; ++mt)
      #pragma unroll
      for (int r = 0; r < 4; ++r) o = fmaf(aw[mt][r], acc[2][ntl][mt][r], o);
    o += __shfl_xor(o, 16, 64);
    o += __shfl_xor(o, 32, 64);
    if (quad == 0)
      attnout[(size_t)bp*Cn + w*64 + ntl*16 + col] = f2b(o * inv);
  }
}

// =====================================================================
// Kernel 3: 64x64-tile fp32 GEMM, D = epi(A@W + bias [+S]). (unchanged)
// =====================================================================
template<bool RELU, bool ADD_S, bool OUT_BF16>
__global__ __launch_bounds__(256) void gemm_kernel(
    const bf16* __restrict__ A, int lda, int Ka,
    const float* __restrict__ W, int N, const float* __restrict__ bias,
    const float* __restrict__ S, void* __restrict__ Dv) {
  __shared__ __align__(16) float As[16][68];
  __shared__ __align__(16) float Bs[16][68];
  const int tile_n = blockIdx.x * 64;
  const int tile_m = blockIdx.y * 64;
  const int tid = threadIdx.x;
  const int tx = tid & 15, ty = tid >> 4;
  float acc[4][4] = {};
  const int nk = (Ka + 15) >> 4;
  for (int kb = 0; kb < nk; ++kb) {
    const int k0 = kb * 16;
    #pragma unroll
    for (int e = tid; e < 1024; e += 256) {
      const int k = e & 15, mm = e >> 4;
      const int kk = k0 + k;
      As[k][mm] = (kk < Ka) ? b2f(A[(size_t)(tile_m+mm)*lda + kk]) : 0.f;
    }
    #pragma unroll
    for (int e = tid; e < 1024; e += 256) {
      const int nn = e & 63, k = e >> 6;
      const int kk = k0 + k;
      Bs[k][nn] = (kk < Ka) ? W[(size_t)kk*N + tile_n + nn] : 0.f;
    }
    __syncthreads();
    #pragma unroll
    for (int k = 0; k < 16; ++k) {
      const float4 aq = *(const float4*)&As[k][ty*4];
      const float4 bq = *(const float4*)&Bs[k][tx*4];
      const float av[4] = {aq.x, aq.y, aq.z, aq.w};
      const float bv[4] = {bq.x, bq.y, bq.z, bq.w};
      #pragma unroll
      for (int i = 0; i < 4; ++i)
        #pragma unroll
        for (int j = 0; j < 4; ++j)
          acc[i][j] = fmaf(av[i], bv[j], acc[i][j]);
    }
    __syncthreads();
  }
  #pragma unroll
  for (int i = 0; i < 4; ++i) {
    const int m = tile_m + ty*4 + i;
    #pragma unroll
    for (int j = 0; j < 4; ++j) {
      const int n = tile_n + tx*4 + j;
      float v = acc[i][j] + bias[n];
      if (RELU) v = fmaxf(v, 0.f);
      if (ADD_S) v += S[(size_t)m*N + n];
      if (OUT_BF16) ((bf16*)Dv)[(size_t)m*N + n] = f2b(v);
      else          ((float*)Dv)[(size_t)m*N + n] = v;
    }
  }
}

// =====================================================================
// Kernel 4: LayerNorm2 over C=256, one wave per row; fp32 in, bf16 out.
// =====================================================================
__global__ __launch_bounds__(64) void ln2_kernel(const float* __restrict__ feat,
                                                 const float* __restrict__ g,
                                                 const float* __restrict__ b,
                                                 bf16* __restrict__ out) {
  const int r = blockIdx.x, lane = threadIdx.x;
  const float4 v = *(const float4*)(feat + (size_t)r*Cn + lane*4);
  float s  = v.x + v.y + v.z + v.w;
  float s2 = v.x*v.x + v.y*v.y + v.z*v.z + v.w*v.w;
  #pragma unroll
  for (int d = 32; d; d >>= 1) { s += __shfl_xor(s, d, 64); s2 += __shfl_xor(s2, d, 64); }
  const float mean = s * (1.f/256.f);
  const float var  = s2 * (1.f/256.f) - mean*mean;
  const float rstd = rsqrtf(var + 1e-3f);
  const float vv[4] = {v.x, v.y, v.z, v.w};
  #pragma unroll
  for (int c = 0; c < 4; ++c) {
    const int col = lane*4 + c;
    out[(size_t)r*Cn + col] = f2b((vv[c] - mean)*rstd*g[col] + b[col]);
  }
}

// =====================================================================
// kernel_launch — fp32 in/out. Workspace (40 MiB, overlays):
//   featB  fp32 [16384*256] @ 0           16 MiB   live to end
//   attnA  bf16 [16384*256] @ 16,777,216   8 MiB   attnout -> ln2out
//   gfmax  bf16 [16384*132] @ 25,165,824   4.33 MiB } dead before fc1
//   idx    int  [16384*32]  @ 29,491,200   2 MiB    } fc1out overlays
//   wfrag  bf16 [122880]    @ 31,588,352 240 KiB    } (attn phase only)
//   fc1out bf16 [16384*512] @ 25,165,824  16 MiB   (ends 41,943,040)
// =====================================================================
extern "C" void kernel_launch(void* const* d_in, const int* in_sizes, int n_in,
                              void* d_out, int out_size, void* d_ws, size_t ws_size,
                              hipStream_t stream) {
  const float* xyz     = (const float*)d_in[0];
  const float* newxyz  = (const float*)d_in[1];
  const float* featin  = (const float*)d_in[2];
  const float* w_qkv   = (const float*)d_in[3];
  const float* proj_w  = (const float*)d_in[4];
  const float* proj_b  = (const float*)d_in[5];
  const float* dense_w = (const float*)d_in[6];
  const float* dense_b = (const float*)d_in[7];
  const float* fc1_w   = (const float*)d_in[8];
  const float* fc1_b   = (const float*)d_in[9];
  const float* fc2_w   = (const float*)d_in[10];
  const float* fc2_b   = (const float*)d_in[11];
  const float* n1g     = (const float*)d_in[12];
  const float* n1b     = (const float*)d_in[13];
  const float* n2g     = (const float*)d_in[14];
  const float* n2b     = (const float*)d_in[15];

  char*  ws     = (char*)d_ws;
  float* featB  = (float*)(ws + 0);
  bf16*  attnA  = (bf16*)(ws + 16777216);
  bf16*  gfmax  = (bf16*)(ws + 25165824);
  int*   idxws  = (int*) (ws + 29491200);
  short* wfrag  = (short*)(ws + 31588352);
  bf16*  fc1out = (bf16*)(ws + 25165824);

  const int M = Bn * NPn;  // 16384

  knn_kernel<<<dim3(M), dim3(256), 0, stream>>>(xyz, newxyz, idxws);
  wqkv_prep_kernel<<<dim3(480), dim3(256), 0, stream>>>(w_qkv, wfrag);
  fused_attn_kernel<<<dim3(M), dim3(256), 0, stream>>>(
      xyz, newxyz, featin, wfrag, n1g, n1b, idxws, attnA, gfmax);
  gemm_kernel<true, false, false><<<dim3(Cn/64, M/64), dim3(256), 0, stream>>>(
      attnA, Cn, Cn, proj_w, Cn, proj_b, nullptr, featB);
  gemm_kernel<true, true, false><<<dim3(Cn/64, M/64), dim3(256), 0, stream>>>(
      gfmax, 132, CGn, dense_w, Cn, dense_b, featB, featB);
  ln2_kernel<<<dim3(M), dim3(64), 0, stream>>>(featB, n2g, n2b, attnA);
  gemm_kernel<true, false, true><<<dim3(512/64, M/64), dim3(256), 0, stream>>>(
      attnA, Cn, Cn, fc1_w, 512, fc1_b, nullptr, fc1out);
  gemm_kernel<false, true, false><<<dim3(Cn/64, M/64), dim3(256), 0, stream>>>(
      fc1out, 512, 512, fc2_w, Cn, fc2_b, featB, d_out);
}

// Round 5
// 1313.548 us; speedup vs baseline: 2.0912x; 1.2819x over previous
//
#include <hip/hip_runtime.h>
#include <hip/hip_bf16.h>

typedef __hip_bfloat16 bf16;

#define Bn   16
#define Nn   4096
#define NPn  1024
#define Kn   32
#define CINn 128
#define CGn  131
#define Cn   256
#define Hn   4
#define KPAD 160   // qkv K padded to 5x32
#define XBS  168   // Xb (bf16) row stride: 336 B, 16B-aligned, conflict-benign
#define XFS  132   // Xf (fp32) row stride

typedef __attribute__((ext_vector_type(8))) short frag_ab;   // 8 bf16
typedef __attribute__((ext_vector_type(4))) float frag_cd;   // 4 fp32

__device__ __forceinline__ float b2f(bf16 x) { return __bfloat162float(x); }
__device__ __forceinline__ bf16  f2b(float x) { return __float2bfloat16(x); }
__device__ __forceinline__ short f2bs(float x) {             // bf16 bits as short
  union { bf16 h; short s; } u; u.h = __float2bfloat16(x); return u.s;
}

// Monotonic float->uint (total order incl. negative d2 from cancellation).
__device__ __forceinline__ unsigned f2ord(float f) {
  unsigned u = __float_as_uint(f);
  return u ^ ((u >> 31) ? 0xffffffffu : 0x80000000u);
}

// =====================================================================
// Kernel 1: KNN, register-cached argmin. Thread tid owns points
// n = s*256+tid (s=0..15) in a 16-entry u64 register array; per selection
// step only the owner invalidates + rescans its 16 regs. LDS use: 32 B.
// Key = (ord(d2)<<32)|n — d2 bit-matches np's (sn - 2*dot) + sx order.
// =====================================================================
__global__ __launch_bounds__(256) void knn_kernel(const float* __restrict__ xyz,
                                                  const float* __restrict__ newxyz,
                                                  int* __restrict__ idx_out) {
  __shared__ unsigned long long wred[4];
  const int bp  = blockIdx.x;
  const int b   = bp >> 10;
  const int tid = threadIdx.x;
  const float qx = newxyz[bp*3 + 0];
  const float qy = newxyz[bp*3 + 1];
  const float qz = newxyz[bp*3 + 2];
  const float sn = __fadd_rn(__fadd_rn(__fmul_rn(qx,qx), __fmul_rn(qy,qy)),
                             __fmul_rn(qz,qz));
  const float* xb = xyz + (size_t)b * Nn * 3;
  unsigned long long key[16];
  unsigned long long lmin = ~0ull;
  #pragma unroll
  for (int s = 0; s < 16; ++s) {
    const int n = s*256 + tid;
    const float xx = xb[n*3 + 0];
    const float xy = xb[n*3 + 1];
    const float xz = xb[n*3 + 2];
    const float sx  = __fadd_rn(__fadd_rn(__fmul_rn(xx,xx), __fmul_rn(xy,xy)),
                                __fmul_rn(xz,xz));
    const float dot = __fadd_rn(__fadd_rn(__fmul_rn(qx,xx), __fmul_rn(qy,xy)),
                                __fmul_rn(qz,xz));
    const float d2 = __fadd_rn(__fsub_rn(sn, __fmul_rn(2.0f, dot)), sx);
    key[s] = ((unsigned long long)f2ord(d2) << 32) | (unsigned)n;
    if (key[s] < lmin) lmin = key[s];
  }
  const int lane = tid & 63, wv = tid >> 6;
  for (int s = 0; s < Kn; ++s) {
    unsigned long long m = lmin;
    #pragma unroll
    for (int d = 32; d; d >>= 1) {   // 64-lane butterfly min (u64 as 2x32)
      const unsigned lo = __shfl_xor((unsigned)(m & 0xffffffffu), d, 64);
      const unsigned hi = __shfl_xor((unsigned)(m >> 32), d, 64);
      const unsigned long long o = ((unsigned long long)hi << 32) | lo;
      if (o < m) m = o;
    }
    if (lane == 0) wred[wv] = m;
    __syncthreads();
    unsigned long long best = wred[0];
    if (wred[1] < best) best = wred[1];
    if (wred[2] < best) best = wred[2];
    if (wred[3] < best) best = wred[3];
    __syncthreads();   // wred consumed; safe to overwrite next iter
    const int n = (int)(best & 0xffffffffu);
    if (tid == 0) idx_out[(size_t)bp*Kn + s] = n;
    if ((n & 255) == tid) {          // owner invalidates + rescans registers
      const int slot = n >> 8;
      #pragma unroll
      for (int t = 0; t < 16; ++t) if (t == slot) key[t] = ~0ull;
      unsigned long long mm = ~0ull;
      #pragma unroll
      for (int t = 0; t < 16; ++t) if (key[t] < mm) mm = key[t];
      lmin = mm;
    }
  }
}

// =====================================================================
// Kernel 1b: pre-swizzle w_qkv (fp32 131x768) into bf16 B-fragment order
// for mfma_f32_16x16x32_bf16 (verified layout, round 4).
// =====================================================================
__global__ __launch_bounds__(256) void wqkv_prep_kernel(const float* __restrict__ w_qkv,
                                                        short* __restrict__ wfrag) {
  const int t = blockIdx.x * 256 + threadIdx.x;   // grid exactly 480*256
  int idx = t;
  const int j    = idx & 7;   idx >>= 3;
  const int lane = idx & 63;  idx >>= 6;
  const int nt   = idx % 48;
  const int kt   = idx / 48;
  const int k = kt*32 + (lane >> 4)*8 + j;
  const int n = nt*16 + (lane & 15);
  wfrag[t] = (k < CGn) ? f2bs(w_qkv[(size_t)k*768 + n]) : (short)0;
}

// =====================================================================
// Kernel 2: fused gather + gf_max + LN1 + MFMA qkv + attention.
// (unchanged from round 4 — verified correct)
// =====================================================================
__global__ __launch_bounds__(256) void fused_attn_kernel(
    const float* __restrict__ xyz, const float* __restrict__ newxyz,
    const float* __restrict__ featin, const short* __restrict__ wfrag,
    const float* __restrict__ n1g, const float* __restrict__ n1b,
    const int* __restrict__ idx, bf16* __restrict__ attnout,
    bf16* __restrict__ gfmax) {
  __shared__ float Xf[Kn * XFS];
  __shared__ __align__(16) short Xb[Kn * XBS];
  __shared__ float smean[Kn], srstd[Kn];
  __shared__ int sidx[Kn];
  const int bp  = blockIdx.x;
  const int b   = bp >> 10;
  const int tid = threadIdx.x;
  if (tid < Kn) {
    int n = idx[(size_t)bp*Kn + tid];
    sidx[tid] = ((unsigned)n < (unsigned)Nn) ? n : 0;
  }
  __syncthreads();
  for (int e = tid; e < Kn*XFS; e += 256) {
    const int kk = e / XFS, j = e % XFS;
    if (j >= CGn) continue;
    const int n = sidx[kk];
    float v;
    if (j < 3) v = xyz[((size_t)b*Nn + n)*3 + j] - newxyz[bp*3 + j];
    else       v = featin[((size_t)b*Nn + n)*CINn + (j-3)];
    Xf[kk*XFS + j] = v;
  }
  __syncthreads();
  if (tid < CGn) {
    float m = -1e30f;
    #pragma unroll
    for (int kk = 0; kk < Kn; ++kk) m = fmaxf(m, Xf[kk*XFS + tid]);
    gfmax[(size_t)bp*132 + tid] = f2b(m);
  }
  if (tid < Kn) {
    float s = 0.f, s2 = 0.f;
    for (int j = 0; j < CGn; ++j) { const float v = Xf[tid*XFS + j]; s += v; s2 += v*v; }
    const float mean = s * (1.0f/CGn);
    const float var  = s2 * (1.0f/CGn) - mean*mean;
    smean[tid] = mean;
    srstd[tid] = rsqrtf(var + 1e-3f);
  }
  __syncthreads();
  for (int e = tid; e < Kn*KPAD; e += 256) {
    const int kk = e / KPAD, j = e % KPAD;
    float v = 0.f;
    if (j < CGn)
      v = (Xf[kk*XFS + j] - smean[kk]) * srstd[kk] * n1g[j] + n1b[j];
    Xb[kk*XBS + j] = f2bs(v);
  }
  __syncthreads();
  const int lane = tid & 63, w = tid >> 6;
  const int col = lane & 15, quad = lane >> 4;
  frag_cd acc[3][4][2] = {};
  for (int kt = 0; kt < 5; ++kt) {
    const int ko = kt*32 + quad*8;
    const frag_ab a0 = *(const frag_ab*)&Xb[ col      *XBS + ko];
    const frag_ab a1 = *(const frag_ab*)&Xb[(16+col)  *XBS + ko];
    #pragma unroll
    for (int part = 0; part < 3; ++part) {
      #pragma unroll
      for (int ntl = 0; ntl < 4; ++ntl) {
        const int nt = part*16 + w*4 + ntl;
        const frag_ab bf = *(const frag_ab*)(wfrag + ((size_t)(kt*48 + nt)*64 + lane)*8);
        acc[part][ntl][0] = __builtin_amdgcn_mfma_f32_16x16x32_bf16(a0, bf, acc[part][ntl][0], 0, 0, 0);
        acc[part][ntl][1] = __builtin_amdgcn_mfma_f32_16x16x32_bf16(a1, bf, acc[part][ntl][1], 0, 0, 0);
      }
    }
  }
  float qm[4];
  #pragma unroll
  for (int ntl = 0; ntl < 4; ++ntl) {
    float m = -1e30f;
    #pragma unroll
    for (int mt = 0; mt < 2; ++mt)
      #pragma unroll
      for (int r = 0; r < 4; ++r) m = fmaxf(m, acc[0][ntl][mt][r]);
    m = fmaxf(m, __shfl_xor(m, 16, 64));
    m = fmaxf(m, __shfl_xor(m, 32, 64));
    qm[ntl] = m;
  }
  float lg[2][4];
  #pragma unroll
  for (int mt = 0; mt < 2; ++mt)
    #pragma unroll
    for (int r = 0; r < 4; ++r) {
      float p = 0.f;
      #pragma unroll
      for (int ntl = 0; ntl < 4; ++ntl) p = fmaf(qm[ntl], acc[1][ntl][mt][r], p);
      #pragma unroll
      for (int d = 1; d < 16; d <<= 1) p += __shfl_xor(p, d, 64);
      lg[mt][r] = p * 0.0625f;
    }
  float mx = -1e30f;
  #pragma unroll
  for (int mt = 0; mt < 2; ++mt)
    #pragma unroll
    for (int r = 0; r < 4; ++r) mx = fmaxf(mx, lg[mt][r]);
  mx = fmaxf(mx, __shfl_xor(mx, 16, 64));
  mx = fmaxf(mx, __shfl_xor(mx, 32, 64));
  float aw[2][4], ssum = 0.f;
  #pragma unroll
  for (int mt = 0; mt < 2; ++mt)
    #pragma unroll
    for (int r = 0; r < 4; ++r) { aw[mt][r] = expf(lg[mt][r] - mx); ssum += aw[mt][r]; }
  ssum += __shfl_xor(ssum, 16, 64);
  ssum += __shfl_xor(ssum, 32, 64);
  const float inv = 1.f / ssum;
  #pragma unroll
  for (int ntl = 0; ntl < 4; ++ntl) {
    float o = 0.f;
    #pragma unroll
    for (int mt = 0; mt < 2; ++mt)
      #pragma unroll
      for (int r = 0; r < 4; ++r) o = fmaf(aw[mt][r], acc[2][ntl][mt][r], o);
    o += __shfl_xor(o, 16, 64);
    o += __shfl_xor(o, 32, 64);
    if (quad == 0)
      attnout[(size_t)bp*Cn + w*64 + ntl*16 + col] = f2b(o * inv);
  }
}

// =====================================================================
// Kernel 3: 64x64-tile fp32 GEMM, D = epi(A@W + bias [+S]). (unchanged)
// =====================================================================
template<bool RELU, bool ADD_S, bool OUT_BF16>
__global__ __launch_bounds__(256) void gemm_kernel(
    const bf16* __restrict__ A, int lda, int Ka,
    const float* __restrict__ W, int N, const float* __restrict__ bias,
    const float* __restrict__ S, void* __restrict__ Dv) {
  __shared__ __align__(16) float As[16][68];
  __shared__ __align__(16) float Bs[16][68];
  const int tile_n = blockIdx.x * 64;
  const int tile_m = blockIdx.y * 64;
  const int tid = threadIdx.x;
  const int tx = tid & 15, ty = tid >> 4;
  float acc[4][4] = {};
  const int nk = (Ka + 15) >> 4;
  for (int kb = 0; kb < nk; ++kb) {
    const int k0 = kb * 16;
    #pragma unroll
    for (int e = tid; e < 1024; e += 256) {
      const int k = e & 15, mm = e >> 4;
      const int kk = k0 + k;
      As[k][mm] = (kk < Ka) ? b2f(A[(size_t)(tile_m+mm)*lda + kk]) : 0.f;
    }
    #pragma unroll
    for (int e = tid; e < 1024; e += 256) {
      const int nn = e & 63, k = e >> 6;
      const int kk = k0 + k;
      Bs[k][nn] = (kk < Ka) ? W[(size_t)kk*N + tile_n + nn] : 0.f;
    }
    __syncthreads();
    #pragma unroll
    for (int k = 0; k < 16; ++k) {
      const float4 aq = *(const float4*)&As[k][ty*4];
      const float4 bq = *(const float4*)&Bs[k][tx*4];
      const float av[4] = {aq.x, aq.y, aq.z, aq.w};
      const float bv[4] = {bq.x, bq.y, bq.z, bq.w};
      #pragma unroll
      for (int i = 0; i < 4; ++i)
        #pragma unroll
        for (int j = 0; j < 4; ++j)
          acc[i][j] = fmaf(av[i], bv[j], acc[i][j]);
    }
    __syncthreads();
  }
  #pragma unroll
  for (int i = 0; i < 4; ++i) {
    const int m = tile_m + ty*4 + i;
    #pragma unroll
    for (int j = 0; j < 4; ++j) {
      const int n = tile_n + tx*4 + j;
      float v = acc[i][j] + bias[n];
      if (RELU) v = fmaxf(v, 0.f);
      if (ADD_S) v += S[(size_t)m*N + n];
      if (OUT_BF16) ((bf16*)Dv)[(size_t)m*N + n] = f2b(v);
      else          ((float*)Dv)[(size_t)m*N + n] = v;
    }
  }
}

// =====================================================================
// Kernel 4: LayerNorm2 over C=256, one wave per row; fp32 in, bf16 out.
// =====================================================================
__global__ __launch_bounds__(64) void ln2_kernel(const float* __restrict__ feat,
                                                 const float* __restrict__ g,
                                                 const float* __restrict__ b,
                                                 bf16* __restrict__ out) {
  const int r = blockIdx.x, lane = threadIdx.x;
  const float4 v = *(const float4*)(feat + (size_t)r*Cn + lane*4);
  float s  = v.x + v.y + v.z + v.w;
  float s2 = v.x*v.x + v.y*v.y + v.z*v.z + v.w*v.w;
  #pragma unroll
  for (int d = 32; d; d >>= 1) { s += __shfl_xor(s, d, 64); s2 += __shfl_xor(s2, d, 64); }
  const float mean = s * (1.f/256.f);
  const float var  = s2 * (1.f/256.f) - mean*mean;
  const float rstd = rsqrtf(var + 1e-3f);
  const float vv[4] = {v.x, v.y, v.z, v.w};
  #pragma unroll
  for (int c = 0; c < 4; ++c) {
    const int col = lane*4 + c;
    out[(size_t)r*Cn + col] = f2b((vv[c] - mean)*rstd*g[col] + b[col]);
  }
}

// =====================================================================
// kernel_launch — fp32 in/out. Workspace (40 MiB, overlays):
//   featB  fp32 [16384*256] @ 0           16 MiB   live to end
//   attnA  bf16 [16384*256] @ 16,777,216   8 MiB   attnout -> ln2out
//   gfmax  bf16 [16384*132] @ 25,165,824   4.33 MiB } dead before fc1
//   idx    int  [16384*32]  @ 29,491,200   2 MiB    } fc1out overlays
//   wfrag  bf16 [122880]    @ 31,588,352 240 KiB    } (attn phase only)
//   fc1out bf16 [16384*512] @ 25,165,824  16 MiB   (ends 41,943,040)
// =====================================================================
extern "C" void kernel_launch(void* const* d_in, const int* in_sizes, int n_in,
                              void* d_out, int out_size, void* d_ws, size_t ws_size,
                              hipStream_t stream) {
  const float* xyz     = (const float*)d_in[0];
  const float* newxyz  = (const float*)d_in[1];
  const float* featin  = (const float*)d_in[2];
  const float* w_qkv   = (const float*)d_in[3];
  const float* proj_w  = (const float*)d_in[4];
  const float* proj_b  = (const float*)d_in[5];
  const float* dense_w = (const float*)d_in[6];
  const float* dense_b = (const float*)d_in[7];
  const float* fc1_w   = (const float*)d_in[8];
  const float* fc1_b   = (const float*)d_in[9];
  const float* fc2_w   = (const float*)d_in[10];
  const float* fc2_b   = (const float*)d_in[11];
  const float* n1g     = (const float*)d_in[12];
  const float* n1b     = (const float*)d_in[13];
  const float* n2g     = (const float*)d_in[14];
  const float* n2b     = (const float*)d_in[15];

  char*  ws     = (char*)d_ws;
  float* featB  = (float*)(ws + 0);
  bf16*  attnA  = (bf16*)(ws + 16777216);
  bf16*  gfmax  = (bf16*)(ws + 25165824);
  int*   idxws  = (int*) (ws + 29491200);
  short* wfrag  = (short*)(ws + 31588352);
  bf16*  fc1out = (bf16*)(ws + 25165824);

  const int M = Bn * NPn;  // 16384

  knn_kernel<<<dim3(M), dim3(256), 0, stream>>>(xyz, newxyz, idxws);
  wqkv_prep_kernel<<<dim3(480), dim3(256), 0, stream>>>(w_qkv, wfrag);
  fused_attn_kernel<<<dim3(M), dim3(256), 0, stream>>>(
      xyz, newxyz, featin, wfrag, n1g, n1b, idxws, attnA, gfmax);
  gemm_kernel<true, false, false><<<dim3(Cn/64, M/64), dim3(256), 0, stream>>>(
      attnA, Cn, Cn, proj_w, Cn, proj_b, nullptr, featB);
  gemm_kernel<true, true, false><<<dim3(Cn/64, M/64), dim3(256), 0, stream>>>(
      gfmax, 132, CGn, dense_w, Cn, dense_b, featB, featB);
  ln2_kernel<<<dim3(M), dim3(64), 0, stream>>>(featB, n2g, n2b, attnA);
  gemm_kernel<true, false, true><<<dim3(512/64, M/64), dim3(256), 0, stream>>>(
      attnA, Cn, Cn, fc1_w, 512, fc1_b, nullptr, fc1out);
  gemm_kernel<false, true, false><<<dim3(Cn/64, M/64), dim3(256), 0, stream>>>(
      fc1out, 512, 512, fc2_w, Cn, fc2_b, featB, d_out);
}

// Round 6
// 1175.893 us; speedup vs baseline: 2.3361x; 1.1171x over previous
//
#include <hip/hip_runtime.h>
#include <hip/hip_bf16.h>

typedef __hip_bfloat16 bf16;

#define Bn   16
#define Nn   4096
#define NPn  1024
#define Kn   32
#define CINn 128
#define CGn  131
#define Cn   256
#define Hn   4
#define KPAD 160   // qkv K padded to 5x32
#define XBS  168   // Xb (bf16) row stride: 336 B, 16B-aligned
#define XFS  132   // Xf (fp32) row stride

typedef __attribute__((ext_vector_type(8))) short frag_ab;   // 8 bf16
typedef __attribute__((ext_vector_type(4))) float frag_cd;   // 4 fp32

__device__ __forceinline__ float b2f(bf16 x) { return __bfloat162float(x); }
__device__ __forceinline__ bf16  f2b(float x) { return __float2bfloat16(x); }
__device__ __forceinline__ short f2bs(float x) {             // bf16 bits as short
  union { bf16 h; short s; } u; u.h = __float2bfloat16(x); return u.s;
}

// Monotonic float->uint (total order incl. negative d2 from cancellation).
__device__ __forceinline__ unsigned f2ord(float f) {
  unsigned u = __float_as_uint(f);
  return u ^ ((u >> 31) ? 0xffffffffu : 0x80000000u);
}

// =====================================================================
// Kernel 1: KNN, register-cached argmin (unchanged from round 5).
// =====================================================================
__global__ __launch_bounds__(256) void knn_kernel(const float* __restrict__ xyz,
                                                  const float* __restrict__ newxyz,
                                                  int* __restrict__ idx_out) {
  __shared__ unsigned long long wred[4];
  const int bp  = blockIdx.x;
  const int b   = bp >> 10;
  const int tid = threadIdx.x;
  const float qx = newxyz[bp*3 + 0];
  const float qy = newxyz[bp*3 + 1];
  const float qz = newxyz[bp*3 + 2];
  const float sn = __fadd_rn(__fadd_rn(__fmul_rn(qx,qx), __fmul_rn(qy,qy)),
                             __fmul_rn(qz,qz));
  const float* xb = xyz + (size_t)b * Nn * 3;
  unsigned long long key[16];
  unsigned long long lmin = ~0ull;
  #pragma unroll
  for (int s = 0; s < 16; ++s) {
    const int n = s*256 + tid;
    const float xx = xb[n*3 + 0];
    const float xy = xb[n*3 + 1];
    const float xz = xb[n*3 + 2];
    const float sx  = __fadd_rn(__fadd_rn(__fmul_rn(xx,xx), __fmul_rn(xy,xy)),
                                __fmul_rn(xz,xz));
    const float dot = __fadd_rn(__fadd_rn(__fmul_rn(qx,xx), __fmul_rn(qy,xy)),
                                __fmul_rn(qz,xz));
    const float d2 = __fadd_rn(__fsub_rn(sn, __fmul_rn(2.0f, dot)), sx);
    key[s] = ((unsigned long long)f2ord(d2) << 32) | (unsigned)n;
    if (key[s] < lmin) lmin = key[s];
  }
  const int lane = tid & 63, wv = tid >> 6;
  for (int s = 0; s < Kn; ++s) {
    unsigned long long m = lmin;
    #pragma unroll
    for (int d = 32; d; d >>= 1) {
      const unsigned lo = __shfl_xor((unsigned)(m & 0xffffffffu), d, 64);
      const unsigned hi = __shfl_xor((unsigned)(m >> 32), d, 64);
      const unsigned long long o = ((unsigned long long)hi << 32) | lo;
      if (o < m) m = o;
    }
    if (lane == 0) wred[wv] = m;
    __syncthreads();
    unsigned long long best = wred[0];
    if (wred[1] < best) best = wred[1];
    if (wred[2] < best) best = wred[2];
    if (wred[3] < best) best = wred[3];
    __syncthreads();
    const int n = (int)(best & 0xffffffffu);
    if (tid == 0) idx_out[(size_t)bp*Kn + s] = n;
    if ((n & 255) == tid) {
      const int slot = n >> 8;
      #pragma unroll
      for (int t = 0; t < 16; ++t) if (t == slot) key[t] = ~0ull;
      unsigned long long mm = ~0ull;
      #pragma unroll
      for (int t = 0; t < 16; ++t) if (key[t] < mm) mm = key[t];
      lmin = mm;
    }
  }
}

// =====================================================================
// Kernel 1b: generic weight pre-swizzle into MFMA B-fragment order.
// Wf[(((kt*nnt + nt)*64 + lane)*8 + j] = bf16(W[kt*32+(lane>>4)*8+j][nt*16+(lane&15)])
// zero for k >= K. Grid: nkt*nnt*2 blocks of 256. (verified layout, r4)
// =====================================================================
__global__ __launch_bounds__(256) void wprep_kernel(const float* __restrict__ W,
                                                    short* __restrict__ out,
                                                    int K, int N, int nnt) {
  const int t = blockIdx.x * 256 + threadIdx.x;
  const int j    = t & 7;
  const int lane = (t >> 3) & 63;
  const int nt   = (t >> 9) % nnt;
  const int kt   = (t >> 9) / nnt;
  const int k = kt*32 + (lane >> 4)*8 + j;
  const int n = nt*16 + (lane & 15);
  out[t] = (k < K) ? f2bs(W[(size_t)k*N + n]) : (short)0;
}

// =====================================================================
// Kernel 2: fused gather + gf_max + LN1 + MFMA qkv + attention.
// r6 change: LN1 stats computed by 8 threads/row + shuffle reduce
// (was: 32 threads serial 131-loop with 8-way bank conflicts).
// =====================================================================
__global__ __launch_bounds__(256) void fused_attn_kernel(
    const float* __restrict__ xyz, const float* __restrict__ newxyz,
    const float* __restrict__ featin, const short* __restrict__ wfrag,
    const float* __restrict__ n1g, const float* __restrict__ n1b,
    const int* __restrict__ idx, bf16* __restrict__ attnout,
    bf16* __restrict__ gfmax) {
  __shared__ float Xf[Kn * XFS];
  __shared__ __align__(16) short Xb[Kn * XBS];
  __shared__ float smean[Kn], srstd[Kn];
  __shared__ int sidx[Kn];
  const int bp  = blockIdx.x;
  const int b   = bp >> 10;
  const int tid = threadIdx.x;
  if (tid < Kn) {
    int n = idx[(size_t)bp*Kn + tid];
    sidx[tid] = ((unsigned)n < (unsigned)Nn) ? n : 0;
  }
  __syncthreads();
  for (int e = tid; e < Kn*XFS; e += 256) {
    const int kk = e / XFS, j = e % XFS;
    if (j >= CGn) continue;
    const int n = sidx[kk];
    float v;
    if (j < 3) v = xyz[((size_t)b*Nn + n)*3 + j] - newxyz[bp*3 + j];
    else       v = featin[((size_t)b*Nn + n)*CINn + (j-3)];
    Xf[kk*XFS + j] = v;
  }
  __syncthreads();
  // gf_max over K (raw, pre-LN): consecutive-j reads, conflict-free
  if (tid < CGn) {
    float m = -1e30f;
    #pragma unroll
    for (int kk = 0; kk < Kn; ++kk) m = fmaxf(m, Xf[kk*XFS + tid]);
    gfmax[(size_t)bp*132 + tid] = f2b(m);
  }
  // LN1 stats: 8 threads per neighbor row, stride-8 reads (<=2-way bank
  // aliasing = free), 3-step shuffle reduce within the 8-lane group.
  {
    const int kk = tid >> 3, sub = tid & 7;
    float s = 0.f, s2 = 0.f;
    for (int j = sub; j < CGn; j += 8) {
      const float v = Xf[kk*XFS + j]; s += v; s2 += v*v;
    }
    s  += __shfl_xor(s, 1, 64);  s  += __shfl_xor(s, 2, 64);  s  += __shfl_xor(s, 4, 64);
    s2 += __shfl_xor(s2, 1, 64); s2 += __shfl_xor(s2, 2, 64); s2 += __shfl_xor(s2, 4, 64);
    if (sub == 0) {
      const float mean = s * (1.0f/CGn);
      const float var  = s2 * (1.0f/CGn) - mean*mean;
      smean[kk] = mean;
      srstd[kk] = rsqrtf(var + 1e-3f);
    }
  }
  __syncthreads();
  for (int e = tid; e < Kn*KPAD; e += 256) {
    const int kk = e / KPAD, j = e % KPAD;
    float v = 0.f;
    if (j < CGn)
      v = (Xf[kk*XFS + j] - smean[kk]) * srstd[kk] * n1g[j] + n1b[j];
    Xb[kk*XBS + j] = f2bs(v);
  }
  __syncthreads();
  const int lane = tid & 63, w = tid >> 6;
  const int col = lane & 15, quad = lane >> 4;
  frag_cd acc[3][4][2] = {};
  for (int kt = 0; kt < 5; ++kt) {
    const int ko = kt*32 + quad*8;
    const frag_ab a0 = *(const frag_ab*)&Xb[ col      *XBS + ko];
    const frag_ab a1 = *(const frag_ab*)&Xb[(16+col)  *XBS + ko];
    #pragma unroll
    for (int part = 0; part < 3; ++part) {
      #pragma unroll
      for (int ntl = 0; ntl < 4; ++ntl) {
        const int nt = part*16 + w*4 + ntl;
        const frag_ab bf = *(const frag_ab*)(wfrag + ((size_t)(kt*48 + nt)*64 + lane)*8);
        acc[part][ntl][0] = __builtin_amdgcn_mfma_f32_16x16x32_bf16(a0, bf, acc[part][ntl][0], 0, 0, 0);
        acc[part][ntl][1] = __builtin_amdgcn_mfma_f32_16x16x32_bf16(a1, bf, acc[part][ntl][1], 0, 0, 0);
      }
    }
  }
  float qm[4];
  #pragma unroll
  for (int ntl = 0; ntl < 4; ++ntl) {
    float m = -1e30f;
    #pragma unroll
    for (int mt = 0; mt < 2; ++mt)
      #pragma unroll
      for (int r = 0; r < 4; ++r) m = fmaxf(m, acc[0][ntl][mt][r]);
    m = fmaxf(m, __shfl_xor(m, 16, 64));
    m = fmaxf(m, __shfl_xor(m, 32, 64));
    qm[ntl] = m;
  }
  float lg[2][4];
  #pragma unroll
  for (int mt = 0; mt < 2; ++mt)
    #pragma unroll
    for (int r = 0; r < 4; ++r) {
      float p = 0.f;
      #pragma unroll
      for (int ntl = 0; ntl < 4; ++ntl) p = fmaf(qm[ntl], acc[1][ntl][mt][r], p);
      #pragma unroll
      for (int d = 1; d < 16; d <<= 1) p += __shfl_xor(p, d, 64);
      lg[mt][r] = p * 0.0625f;
    }
  float mx = -1e30f;
  #pragma unroll
  for (int mt = 0; mt < 2; ++mt)
    #pragma unroll
    for (int r = 0; r < 4; ++r) mx = fmaxf(mx, lg[mt][r]);
  mx = fmaxf(mx, __shfl_xor(mx, 16, 64));
  mx = fmaxf(mx, __shfl_xor(mx, 32, 64));
  float aw[2][4], ssum = 0.f;
  #pragma unroll
  for (int mt = 0; mt < 2; ++mt)
    #pragma unroll
    for (int r = 0; r < 4; ++r) { aw[mt][r] = expf(lg[mt][r] - mx); ssum += aw[mt][r]; }
  ssum += __shfl_xor(ssum, 16, 64);
  ssum += __shfl_xor(ssum, 32, 64);
  const float inv = 1.f / ssum;
  #pragma unroll
  for (int ntl = 0; ntl < 4; ++ntl) {
    float o = 0.f;
    #pragma unroll
    for (int mt = 0; mt < 2; ++mt)
      #pragma unroll
      for (int r = 0; r < 4; ++r) o = fmaf(aw[mt][r], acc[2][ntl][mt][r], o);
    o += __shfl_xor(o, 16, 64);
    o += __shfl_xor(o, 32, 64);
    if (quad == 0)
      attnout[(size_t)bp*Cn + w*64 + ntl*16 + col] = f2b(o * inv);
  }
}

// =====================================================================
// Kernel 3: MFMA GEMM, D = epi(A@W + bias [+S]). A bf16 (M x Ka, row
// stride lda); W pre-swizzled bf16 fragments; fp32 accumulate.
// Block = 64 rows x 256 cols (wave w owns cols w*64..w*64+63).
// Grid: (N/256, M/64).
// =====================================================================
template<bool RELU, bool ADD_S, bool OUT_BF16>
__global__ __launch_bounds__(256) void mfma_gemm_kernel(
    const bf16* __restrict__ A, int lda, int Ka,
    const short* __restrict__ Wf, int nnt_total, int N,
    const float* __restrict__ bias, const bf16* __restrict__ S,
    void* __restrict__ Dv) {
  __shared__ __align__(16) short As[64*40];   // 64 rows x 32 k, stride 40
  const int m0   = blockIdx.y * 64;
  const int nblk = blockIdx.x;
  const int tid  = threadIdx.x;
  const int lane = tid & 63, w = tid >> 6;
  const int col = lane & 15, quad = lane >> 4;
  frag_cd acc[4][4] = {};                     // [mt][ntl]
  const int nkt = (Ka + 31) >> 5;
  for (int kt = 0; kt < nkt; ++kt) {
    #pragma unroll
    for (int e = tid; e < 2048; e += 256) {
      const int row = e >> 5, c = e & 31;
      const int k = kt*32 + c;
      As[row*40 + c] = (k < Ka) ? ((const short*)A)[(size_t)(m0+row)*lda + k] : (short)0;
    }
    __syncthreads();
    frag_ab afr[4];
    #pragma unroll
    for (int mt = 0; mt < 4; ++mt)
      afr[mt] = *(const frag_ab*)&As[(mt*16 + col)*40 + quad*8];
    #pragma unroll
    for (int ntl = 0; ntl < 4; ++ntl) {
      const int nt = nblk*16 + w*4 + ntl;
      const frag_ab bfr = *(const frag_ab*)(Wf + ((size_t)(kt*nnt_total + nt)*64 + lane)*8);
      #pragma unroll
      for (int mt = 0; mt < 4; ++mt)
        acc[mt][ntl] = __builtin_amdgcn_mfma_f32_16x16x32_bf16(afr[mt], bfr, acc[mt][ntl], 0, 0, 0);
    }
    __syncthreads();
  }
  // epilogue: C layout col(n)=lane&15, row(m)=quad*4+r (verified m89/r4)
  #pragma unroll
  for (int ntl = 0; ntl < 4; ++ntl) {
    const int n = nblk*256 + w*64 + ntl*16 + col;
    const float bv = bias[n];
    #pragma unroll
    for (int mt = 0; mt < 4; ++mt) {
      #pragma unroll
      for (int r = 0; r < 4; ++r) {
        const int m = m0 + mt*16 + quad*4 + r;
        float v = acc[mt][ntl][r] + bv;
        if (RELU) v = fmaxf(v, 0.f);
        if (ADD_S) v += b2f(S[(size_t)m*N + n]);
        if (OUT_BF16) ((bf16*)Dv)[(size_t)m*N + n] = f2b(v);
        else          ((float*)Dv)[(size_t)m*N + n] = v;
      }
    }
  }
}

// =====================================================================
// Kernel 4: LayerNorm2 over C=256, one wave per row; bf16 in/out.
// =====================================================================
__global__ __launch_bounds__(64) void ln2_kernel(const bf16* __restrict__ feat,
                                                 const float* __restrict__ g,
                                                 const float* __restrict__ b,
                                                 bf16* __restrict__ out) {
  const int r = blockIdx.x, lane = threadIdx.x;
  float vv[4];
  #pragma unroll
  for (int c = 0; c < 4; ++c) vv[c] = b2f(feat[(size_t)r*Cn + lane*4 + c]);
  float s  = vv[0] + vv[1] + vv[2] + vv[3];
  float s2 = vv[0]*vv[0] + vv[1]*vv[1] + vv[2]*vv[2] + vv[3]*vv[3];
  #pragma unroll
  for (int d = 32; d; d >>= 1) { s += __shfl_xor(s, d, 64); s2 += __shfl_xor(s2, d, 64); }
  const float mean = s * (1.f/256.f);
  const float var  = s2 * (1.f/256.f) - mean*mean;
  const float rstd = rsqrtf(var + 1e-3f);
  #pragma unroll
  for (int c = 0; c < 4; ++c) {
    const int col = lane*4 + c;
    out[(size_t)r*Cn + col] = f2b((vv[c] - mean)*rstd*g[col] + b[col]);
  }
}

// =====================================================================
// kernel_launch — fp32 in/out. Workspace (peak 41.03 MB < 41.94 proven):
//   wqkv   @ 0          245,760 B   } weight frags, live whole session
//   wproj  @ 245,760    131,072 B
//   wdense @ 376,832     81,920 B
//   wfc1   @ 458,752    262,144 B
//   wfc2   @ 720,896    262,144 B   (end 983,040; pad to 1 MiB)
//   featB  bf16 [16384*256] @  1,048,576   8 MiB  residual, live to end
//   attnA  bf16 [16384*256] @  9,437,184   8 MiB  attnout -> ln2out
//   gfmax  bf16 [16384*132] @ 17,825,792   4.33 MiB } dead before fc1
//   idx    int  [16384*32]  @ 22,151,168   2 MiB    } fc1out overlays
//   fc1out bf16 [16384*512] @ 24,248,320  16 MiB  (ends 41,025,536)
// =====================================================================
extern "C" void kernel_launch(void* const* d_in, const int* in_sizes, int n_in,
                              void* d_out, int out_size, void* d_ws, size_t ws_size,
                              hipStream_t stream) {
  const float* xyz     = (const float*)d_in[0];
  const float* newxyz  = (const float*)d_in[1];
  const float* featin  = (const float*)d_in[2];
  const float* w_qkv   = (const float*)d_in[3];
  const float* proj_w  = (const float*)d_in[4];
  const float* proj_b  = (const float*)d_in[5];
  const float* dense_w = (const float*)d_in[6];
  const float* dense_b = (const float*)d_in[7];
  const float* fc1_w   = (const float*)d_in[8];
  const float* fc1_b   = (const float*)d_in[9];
  const float* fc2_w   = (const float*)d_in[10];
  const float* fc2_b   = (const float*)d_in[11];
  const float* n1g     = (const float*)d_in[12];
  const float* n1b     = (const float*)d_in[13];
  const float* n2g     = (const float*)d_in[14];
  const float* n2b     = (const float*)d_in[15];

  char*  ws     = (char*)d_ws;
  short* wqkv   = (short*)(ws + 0);
  short* wproj  = (short*)(ws + 245760);
  short* wdense = (short*)(ws + 376832);
  short* wfc1   = (short*)(ws + 458752);
  short* wfc2   = (short*)(ws + 720896);
  bf16*  featB  = (bf16*)(ws + 1048576);
  bf16*  attnA  = (bf16*)(ws + 9437184);
  bf16*  gfmax  = (bf16*)(ws + 17825792);
  int*   idxws  = (int*) (ws + 22151168);
  bf16*  fc1out = (bf16*)(ws + 24248320);

  const int M = Bn * NPn;  // 16384

  knn_kernel<<<dim3(M), dim3(256), 0, stream>>>(xyz, newxyz, idxws);
  // weight pre-swizzles (grid = nkt*nnt*2)
  wprep_kernel<<<dim3(480), dim3(256), 0, stream>>>(w_qkv,   wqkv,   CGn, 768, 48);
  wprep_kernel<<<dim3(256), dim3(256), 0, stream>>>(proj_w,  wproj,  Cn,  256, 16);
  wprep_kernel<<<dim3(160), dim3(256), 0, stream>>>(dense_w, wdense, CGn, 256, 16);
  wprep_kernel<<<dim3(512), dim3(256), 0, stream>>>(fc1_w,   wfc1,   Cn,  512, 32);
  wprep_kernel<<<dim3(512), dim3(256), 0, stream>>>(fc2_w,   wfc2,   512, 256, 16);

  fused_attn_kernel<<<dim3(M), dim3(256), 0, stream>>>(
      xyz, newxyz, featin, wqkv, n1g, n1b, idxws, attnA, gfmax);
  // featB = relu(attn @ proj_w + proj_b)
  mfma_gemm_kernel<true, false, true><<<dim3(1, M/64), dim3(256), 0, stream>>>(
      attnA, Cn, Cn, wproj, 16, Cn, proj_b, (const bf16*)nullptr, featB);
  // featB += relu(gfmax @ dense_w + dense_b)  (elementwise in-place)
  mfma_gemm_kernel<true, true, true><<<dim3(1, M/64), dim3(256), 0, stream>>>(
      gfmax, 132, CGn, wdense, 16, Cn, dense_b, featB, featB);
  // attnA <- LN2(featB)
  ln2_kernel<<<dim3(M), dim3(64), 0, stream>>>(featB, n2g, n2b, attnA);
  // fc1out = relu(attnA @ fc1 + b1)
  mfma_gemm_kernel<true, false, true><<<dim3(2, M/64), dim3(256), 0, stream>>>(
      attnA, Cn, Cn, wfc1, 32, 512, fc1_b, (const bf16*)nullptr, fc1out);
  // out = fc1out @ fc2 + b2 + featB   (fp32 output)
  mfma_gemm_kernel<false, true, false><<<dim3(1, M/64), dim3(256), 0, stream>>>(
      fc1out, 512, 512, wfc2, 16, Cn, fc2_b, featB, d_out);
}

// Round 7
// 910.165 us; speedup vs baseline: 3.0181x; 1.2920x over previous
//
#include <hip/hip_runtime.h>
#include <hip/hip_bf16.h>

typedef __hip_bfloat16 bf16;

#define Bn   16
#define Nn   4096
#define NPn  1024
#define Kn   32
#define CINn 128
#define CGn  131
#define Cn   256
#define Hn   4
#define KPAD 160   // qkv K padded to 5x32 (internal order: feat 0..127, xyz 128..130)
#define XBS  168   // Xb (bf16) row stride
#define XFS  132   // Xf (fp32) row stride
#define GFS  136   // gfmax row stride (bf16), 272 B = 16-aligned, pads zeroed

typedef __attribute__((ext_vector_type(8))) short frag_ab;   // 8 bf16
typedef __attribute__((ext_vector_type(4))) float frag_cd;   // 4 fp32

__device__ __forceinline__ float b2f(bf16 x) { return __bfloat162float(x); }
__device__ __forceinline__ bf16  f2b(float x) { return __float2bfloat16(x); }
__device__ __forceinline__ short f2bs(float x) {
  union { bf16 h; short s; } u; u.h = __float2bfloat16(x); return u.s;
}
__device__ __forceinline__ unsigned f2ord(float f) {
  unsigned u = __float_as_uint(f);
  return u ^ ((u >> 31) ? 0xffffffffu : 0x80000000u);
}

// =====================================================================
// Kernel 1: KNN, register-cached argmin (unchanged — verified r5/r6).
// =====================================================================
__global__ __launch_bounds__(256) void knn_kernel(const float* __restrict__ xyz,
                                                  const float* __restrict__ newxyz,
                                                  int* __restrict__ idx_out) {
  __shared__ unsigned long long wred[4];
  const int bp  = blockIdx.x;
  const int b   = bp >> 10;
  const int tid = threadIdx.x;
  const float qx = newxyz[bp*3 + 0];
  const float qy = newxyz[bp*3 + 1];
  const float qz = newxyz[bp*3 + 2];
  const float sn = __fadd_rn(__fadd_rn(__fmul_rn(qx,qx), __fmul_rn(qy,qy)),
                             __fmul_rn(qz,qz));
  const float* xb = xyz + (size_t)b * Nn * 3;
  unsigned long long key[16];
  unsigned long long lmin = ~0ull;
  #pragma unroll
  for (int s = 0; s < 16; ++s) {
    const int n = s*256 + tid;
    const float xx = xb[n*3 + 0];
    const float xy = xb[n*3 + 1];
    const float xz = xb[n*3 + 2];
    const float sx  = __fadd_rn(__fadd_rn(__fmul_rn(xx,xx), __fmul_rn(xy,xy)),
                                __fmul_rn(xz,xz));
    const float dot = __fadd_rn(__fadd_rn(__fmul_rn(qx,xx), __fmul_rn(qy,xy)),
                                __fmul_rn(qz,xz));
    const float d2 = __fadd_rn(__fsub_rn(sn, __fmul_rn(2.0f, dot)), sx);
    key[s] = ((unsigned long long)f2ord(d2) << 32) | (unsigned)n;
    if (key[s] < lmin) lmin = key[s];
  }
  const int lane = tid & 63, wv = tid >> 6;
  for (int s = 0; s < Kn; ++s) {
    unsigned long long m = lmin;
    #pragma unroll
    for (int d = 32; d; d >>= 1) {
      const unsigned lo = __shfl_xor((unsigned)(m & 0xffffffffu), d, 64);
      const unsigned hi = __shfl_xor((unsigned)(m >> 32), d, 64);
      const unsigned long long o = ((unsigned long long)hi << 32) | lo;
      if (o < m) m = o;
    }
    if (lane == 0) wred[wv] = m;
    __syncthreads();
    unsigned long long best = wred[0];
    if (wred[1] < best) best = wred[1];
    if (wred[2] < best) best = wred[2];
    if (wred[3] < best) best = wred[3];
    __syncthreads();
    const int n = (int)(best & 0xffffffffu);
    if (tid == 0) idx_out[(size_t)bp*Kn + s] = n;
    if ((n & 255) == tid) {
      const int slot = n >> 8;
      #pragma unroll
      for (int t = 0; t < 16; ++t) if (t == slot) key[t] = ~0ull;
      unsigned long long mm = ~0ull;
      #pragma unroll
      for (int t = 0; t < 16; ++t) if (key[t] < mm) mm = key[t];
      lmin = mm;
    }
  }
}

// =====================================================================
// Kernel 1b: weight pre-swizzle into MFMA B-fragment order (r4-verified).
// remap!=0: k-rows are in INTERNAL order (feat 0..127 -> ref row k+3,
// xyz 128..130 -> ref row k-128) to match the feat-first gather layout.
// =====================================================================
__global__ __launch_bounds__(256) void wprep_kernel(const float* __restrict__ W,
                                                    short* __restrict__ out,
                                                    int K, int N, int nnt, int remap) {
  const int t = blockIdx.x * 256 + threadIdx.x;
  const int j    = t & 7;
  const int lane = (t >> 3) & 63;
  const int nt   = (t >> 9) % nnt;
  const int kt   = (t >> 9) / nnt;
  const int k = kt*32 + (lane >> 4)*8 + j;
  const int n = nt*16 + (lane & 15);
  int krow = k;
  if (remap) krow = (k < 128) ? k + 3 : k - 128;
  out[t] = (k < K) ? f2bs(W[(size_t)krow*N + n]) : (short)0;
}

// =====================================================================
// Kernel 2: fused gather + gf_max + LN1 + MFMA qkv + attention.
// r7: latency-fixed gather (8 thr/row x 4 float4, unrolled, coalesced),
// LN params cached in LDS, Xb loop exact-unrolled. Internal feature
// order = [feat(128), xyz(3)]; wqkv/wdense row-remapped to match.
// =====================================================================
__global__ __launch_bounds__(256) void fused_attn_kernel(
    const float* __restrict__ xyz, const float* __restrict__ newxyz,
    const float* __restrict__ featin, const short* __restrict__ wfrag,
    const float* __restrict__ n1g, const float* __restrict__ n1b,
    const int* __restrict__ idx, bf16* __restrict__ attnout,
    bf16* __restrict__ gfmax) {
  __shared__ __align__(16) float Xf[Kn * XFS];
  __shared__ __align__(16) short Xb[Kn * XBS];
  __shared__ float smean[Kn], srstd[Kn];
  __shared__ float sg[CGn], sb[CGn];
  __shared__ int sidx[Kn];
  const int bp  = blockIdx.x;
  const int b   = bp >> 10;
  const int tid = threadIdx.x;
  if (tid < Kn) {
    int n = idx[(size_t)bp*Kn + tid];
    sidx[tid] = ((unsigned)n < (unsigned)Nn) ? n : 0;
  }
  if (tid < CGn) {   // LN params, ref->internal: internal j<128 = ref j+3
    const int rj = (tid < 128) ? tid + 3 : tid - 128;
    sg[tid] = n1g[rj];
    sb[tid] = n1b[rj];
  }
  __syncthreads();
  // ---- gather, latency-friendly: 8 threads/row, 4 float4 each ----
  {
    const int kk = tid >> 3, sub = tid & 7;
    const float* frow = featin + ((size_t)b*Nn + sidx[kk])*CINn;
    float4 r[4];
    #pragma unroll
    for (int i = 0; i < 4; ++i) r[i] = *(const float4*)(frow + (sub + 8*i)*4);
    #pragma unroll
    for (int i = 0; i < 4; ++i) *(float4*)&Xf[kk*XFS + (sub + 8*i)*4] = r[i];
  }
  if (tid < 128) {   // xyz -> internal j 128..130
    const int kk = tid >> 2, d = tid & 3;
    if (d < 3)
      Xf[kk*XFS + 128 + d] = xyz[((size_t)b*Nn + sidx[kk])*3 + d] - newxyz[bp*3 + d];
  }
  __syncthreads();
  // gf_max (internal order, stride GFS=136, pads zeroed for GEMM staging)
  if (tid < GFS) {
    float m = 0.f;
    if (tid < CGn) {
      m = -1e30f;
      #pragma unroll
      for (int kk = 0; kk < Kn; ++kk) m = fmaxf(m, Xf[kk*XFS + tid]);
    }
    gfmax[(size_t)bp*GFS + tid] = f2b(m);
  }
  // LN1 stats: 8 threads/row + shuffle reduce
  {
    const int kk = tid >> 3, sub = tid & 7;
    float s = 0.f, s2 = 0.f;
    for (int j = sub; j < CGn; j += 8) {
      const float v = Xf[kk*XFS + j]; s += v; s2 += v*v;
    }
    s  += __shfl_xor(s, 1, 64);  s  += __shfl_xor(s, 2, 64);  s  += __shfl_xor(s, 4, 64);
    s2 += __shfl_xor(s2, 1, 64); s2 += __shfl_xor(s2, 2, 64); s2 += __shfl_xor(s2, 4, 64);
    if (sub == 0) {
      const float mean = s * (1.0f/CGn);
      const float var  = s2 * (1.0f/CGn) - mean*mean;
      smean[kk] = mean;
      srstd[kk] = rsqrtf(var + 1e-3f);
    }
  }
  __syncthreads();
  #pragma unroll
  for (int u = 0; u < 20; ++u) {   // Kn*KPAD/256 = 20 exact, LDS-only
    const int e = u*256 + tid;
    const int kk = e / KPAD, j = e % KPAD;
    float v = 0.f;
    if (j < CGn)
      v = (Xf[kk*XFS + j] - smean[kk]) * srstd[kk] * sg[j] + sb[j];
    Xb[kk*XBS + j] = f2bs(v);
  }
  __syncthreads();
  // ---- MFMA qkv + in-register attention (r4-verified) ----
  const int lane = tid & 63, w = tid >> 6;
  const int col = lane & 15, quad = lane >> 4;
  frag_cd acc[3][4][2] = {};
  for (int kt = 0; kt < 5; ++kt) {
    const int ko = kt*32 + quad*8;
    const frag_ab a0 = *(const frag_ab*)&Xb[ col     *XBS + ko];
    const frag_ab a1 = *(const frag_ab*)&Xb[(16+col) *XBS + ko];
    #pragma unroll
    for (int part = 0; part < 3; ++part) {
      #pragma unroll
      for (int ntl = 0; ntl < 4; ++ntl) {
        const int nt = part*16 + w*4 + ntl;
        const frag_ab bfr = *(const frag_ab*)(wfrag + ((size_t)(kt*48 + nt)*64 + lane)*8);
        acc[part][ntl][0] = __builtin_amdgcn_mfma_f32_16x16x32_bf16(a0, bfr, acc[part][ntl][0], 0, 0, 0);
        acc[part][ntl][1] = __builtin_amdgcn_mfma_f32_16x16x32_bf16(a1, bfr, acc[part][ntl][1], 0, 0, 0);
      }
    }
  }
  float qm[4];
  #pragma unroll
  for (int ntl = 0; ntl < 4; ++ntl) {
    float m = -1e30f;
    #pragma unroll
    for (int mt = 0; mt < 2; ++mt)
      #pragma unroll
      for (int r = 0; r < 4; ++r) m = fmaxf(m, acc[0][ntl][mt][r]);
    m = fmaxf(m, __shfl_xor(m, 16, 64));
    m = fmaxf(m, __shfl_xor(m, 32, 64));
    qm[ntl] = m;
  }
  float lg[2][4];
  #pragma unroll
  for (int mt = 0; mt < 2; ++mt)
    #pragma unroll
    for (int r = 0; r < 4; ++r) {
      float p = 0.f;
      #pragma unroll
      for (int ntl = 0; ntl < 4; ++ntl) p = fmaf(qm[ntl], acc[1][ntl][mt][r], p);
      #pragma unroll
      for (int d = 1; d < 16; d <<= 1) p += __shfl_xor(p, d, 64);
      lg[mt][r] = p * 0.0625f;
    }
  float mx = -1e30f;
  #pragma unroll
  for (int mt = 0; mt < 2; ++mt)
    #pragma unroll
    for (int r = 0; r < 4; ++r) mx = fmaxf(mx, lg[mt][r]);
  mx = fmaxf(mx, __shfl_xor(mx, 16, 64));
  mx = fmaxf(mx, __shfl_xor(mx, 32, 64));
  float aw[2][4], ssum = 0.f;
  #pragma unroll
  for (int mt = 0; mt < 2; ++mt)
    #pragma unroll
    for (int r = 0; r < 4; ++r) { aw[mt][r] = expf(lg[mt][r] - mx); ssum += aw[mt][r]; }
  ssum += __shfl_xor(ssum, 16, 64);
  ssum += __shfl_xor(ssum, 32, 64);
  const float inv = 1.f / ssum;
  #pragma unroll
  for (int ntl = 0; ntl < 4; ++ntl) {
    float o = 0.f;
    #pragma unroll
    for (int mt = 0; mt < 2; ++mt)
      #pragma unroll
      for (int r = 0; r < 4; ++r) o = fmaf(aw[mt][r], acc[2][ntl][mt][r], o);
    o += __shfl_xor(o, 16, 64);
    o += __shfl_xor(o, 32, 64);
    if (quad == 0)
      attnout[(size_t)bp*Cn + w*64 + ntl*16 + col] = f2b(o * inv);
  }
}

// =====================================================================
// Kernel 3: MFMA GEMM, 64x128 tile (wave w -> 2 N-tiles). Vectorized
// staging: 1x16B global load + 1x ds_write_b128 per thread per kt.
// =====================================================================
template<bool RELU, bool ADD_S, bool OUT_BF16>
__global__ __launch_bounds__(256) void mfma_gemm_kernel(
    const bf16* __restrict__ A, int lda, int Ka,
    const short* __restrict__ Wf, int nnt_total, int N,
    const float* __restrict__ bias, const bf16* __restrict__ S,
    void* __restrict__ Dv) {
  __shared__ __align__(16) short As[64*40];
  const int m0 = blockIdx.y * 64;
  const int n0 = blockIdx.x * 128;
  const int tid = threadIdx.x, lane = tid & 63, w = tid >> 6;
  const int col = lane & 15, quad = lane >> 4;
  const int row = tid >> 2, c8 = (tid & 3) * 8;
  frag_cd acc[4][2] = {};
  const int nkt = (Ka + 31) >> 5;
  for (int kt = 0; kt < nkt; ++kt) {
    const int k0 = kt*32 + c8;
    frag_ab av = {0,0,0,0,0,0,0,0};
    if (k0 + 8 <= Ka)
      av = *(const frag_ab*)((const short*)A + (size_t)(m0+row)*lda + k0);
    __syncthreads();
    *(frag_ab*)&As[row*40 + c8] = av;
    __syncthreads();
    frag_ab afr[4];
    #pragma unroll
    for (int mt = 0; mt < 4; ++mt)
      afr[mt] = *(const frag_ab*)&As[(mt*16 + col)*40 + quad*8];
    #pragma unroll
    for (int ntl = 0; ntl < 2; ++ntl) {
      const int nt = (n0 >> 4) + w*2 + ntl;
      const frag_ab bfr = *(const frag_ab*)(Wf + ((size_t)(kt*nnt_total + nt)*64 + lane)*8);
      #pragma unroll
      for (int mt = 0; mt < 4; ++mt)
        acc[mt][ntl] = __builtin_amdgcn_mfma_f32_16x16x32_bf16(afr[mt], bfr, acc[mt][ntl], 0, 0, 0);
    }
  }
  #pragma unroll
  for (int ntl = 0; ntl < 2; ++ntl) {
    const int n = n0 + w*32 + ntl*16 + col;
    const float bv = bias[n];
    #pragma unroll
    for (int mt = 0; mt < 4; ++mt) {
      #pragma unroll
      for (int r = 0; r < 4; ++r) {
        const int m = m0 + mt*16 + quad*4 + r;
        float v = acc[mt][ntl][r] + bv;
        if (RELU) v = fmaxf(v, 0.f);
        if (ADD_S) v += b2f(S[(size_t)m*N + n]);
        if (OUT_BF16) ((bf16*)Dv)[(size_t)m*N + n] = f2b(v);
        else          ((float*)Dv)[(size_t)m*N + n] = v;
      }
    }
  }
}

// =====================================================================
// Kernel 3b: dual GEMM, featB = relu(attn@proj+pb) + relu(gfmax@dense+db).
// Saves one 8 MB featB round-trip + a dispatch vs two kernels.
// =====================================================================
__global__ __launch_bounds__(256) void dual_gemm_kernel(
    const bf16* __restrict__ A1, const short* __restrict__ W1,
    const bf16* __restrict__ A2, const short* __restrict__ W2,
    const float* __restrict__ b1, const float* __restrict__ b2,
    bf16* __restrict__ D) {
  __shared__ __align__(16) short As[64*40];
  const int m0 = blockIdx.y * 64;
  const int n0 = blockIdx.x * 128;
  const int tid = threadIdx.x, lane = tid & 63, w = tid >> 6;
  const int col = lane & 15, quad = lane >> 4;
  const int row = tid >> 2, c8 = (tid & 3) * 8;
  frag_cd acc1[4][2] = {}, acc2[4][2] = {};
  for (int kt = 0; kt < 8; ++kt) {              // A1: Ka=256, lda=256
    const frag_ab av = *(const frag_ab*)((const short*)A1 + (size_t)(m0+row)*Cn + kt*32 + c8);
    __syncthreads();
    *(frag_ab*)&As[row*40 + c8] = av;
    __syncthreads();
    frag_ab afr[4];
    #pragma unroll
    for (int mt = 0; mt < 4; ++mt)
      afr[mt] = *(const frag_ab*)&As[(mt*16 + col)*40 + quad*8];
    #pragma unroll
    for (int ntl = 0; ntl < 2; ++ntl) {
      const int nt = (n0 >> 4) + w*2 + ntl;
      const frag_ab bfr = *(const frag_ab*)(W1 + ((size_t)(kt*16 + nt)*64 + lane)*8);
      #pragma unroll
      for (int mt = 0; mt < 4; ++mt)
        acc1[mt][ntl] = __builtin_amdgcn_mfma_f32_16x16x32_bf16(afr[mt], bfr, acc1[mt][ntl], 0, 0, 0);
    }
  }
  for (int kt = 0; kt < 5; ++kt) {              // A2: Ka=131 (stride GFS, pads 0)
    const int k0 = kt*32 + c8;
    frag_ab av = {0,0,0,0,0,0,0,0};
    if (k0 + 8 <= GFS)
      av = *(const frag_ab*)((const short*)A2 + (size_t)(m0+row)*GFS + k0);
    __syncthreads();
    *(frag_ab*)&As[row*40 + c8] = av;
    __syncthreads();
    frag_ab afr[4];
    #pragma unroll
    for (int mt = 0; mt < 4; ++mt)
      afr[mt] = *(const frag_ab*)&As[(mt*16 + col)*40 + quad*8];
    #pragma unroll
    for (int ntl = 0; ntl < 2; ++ntl) {
      const int nt = (n0 >> 4) + w*2 + ntl;
      const frag_ab bfr = *(const frag_ab*)(W2 + ((size_t)(kt*16 + nt)*64 + lane)*8);
      #pragma unroll
      for (int mt = 0; mt < 4; ++mt)
        acc2[mt][ntl] = __builtin_amdgcn_mfma_f32_16x16x32_bf16(afr[mt], bfr, acc2[mt][ntl], 0, 0, 0);
    }
  }
  #pragma unroll
  for (int ntl = 0; ntl < 2; ++ntl) {
    const int n = n0 + w*32 + ntl*16 + col;
    const float bv1 = b1[n], bv2 = b2[n];
    #pragma unroll
    for (int mt = 0; mt < 4; ++mt) {
      #pragma unroll
      for (int r = 0; r < 4; ++r) {
        const int m = m0 + mt*16 + quad*4 + r;
        const float v = fmaxf(acc1[mt][ntl][r] + bv1, 0.f)
                      + fmaxf(acc2[mt][ntl][r] + bv2, 0.f);
        D[(size_t)m*Cn + n] = f2b(v);
      }
    }
  }
}

// =====================================================================
// Kernel 4: LayerNorm2 over C=256, 4 rows/block (wave per row), bf16.
// =====================================================================
__global__ __launch_bounds__(256) void ln2_kernel(const bf16* __restrict__ feat,
                                                  const float* __restrict__ g,
                                                  const float* __restrict__ b,
                                                  bf16* __restrict__ out) {
  const int r = blockIdx.x*4 + (threadIdx.x >> 6), lane = threadIdx.x & 63;
  float vv[4];
  #pragma unroll
  for (int c = 0; c < 4; ++c) vv[c] = b2f(feat[(size_t)r*Cn + lane*4 + c]);
  float s  = vv[0] + vv[1] + vv[2] + vv[3];
  float s2 = vv[0]*vv[0] + vv[1]*vv[1] + vv[2]*vv[2] + vv[3]*vv[3];
  #pragma unroll
  for (int d = 32; d; d >>= 1) { s += __shfl_xor(s, d, 64); s2 += __shfl_xor(s2, d, 64); }
  const float mean = s * (1.f/256.f);
  const float var  = s2 * (1.f/256.f) - mean*mean;
  const float rstd = rsqrtf(var + 1e-3f);
  #pragma unroll
  for (int c = 0; c < 4; ++c) {
    const int cc = lane*4 + c;
    out[(size_t)r*Cn + cc] = f2b((vv[c] - mean)*rstd*g[cc] + b[cc]);
  }
}

// =====================================================================
// kernel_launch — fp32 in/out. Workspace (peak 41.16 MB < 41.94 proven):
//   wqkv   @ 0          245,760   wproj @ 245,760  131,072
//   wdense @ 376,832     81,920   wfc1  @ 458,752  262,144
//   wfc2   @ 720,896    262,144   (pad to 1 MiB)
//   featB  bf16 [16384*256] @  1,048,576   8 MiB  residual, live to end
//   attnA  bf16 [16384*256] @  9,437,184   8 MiB  attnout -> ln2out
//   gfmax  bf16 [16384*136] @ 17,825,792   4.46 MiB } dead before fc1
//   idx    int  [16384*32]  @ 22,282,240   2 MiB    } fc1out overlays
//   fc1out bf16 [16384*512] @ 24,379,392  16 MiB  (ends 41,156,608)
// =====================================================================
extern "C" void kernel_launch(void* const* d_in, const int* in_sizes, int n_in,
                              void* d_out, int out_size, void* d_ws, size_t ws_size,
                              hipStream_t stream) {
  const float* xyz     = (const float*)d_in[0];
  const float* newxyz  = (const float*)d_in[1];
  const float* featin  = (const float*)d_in[2];
  const float* w_qkv   = (const float*)d_in[3];
  const float* proj_w  = (const float*)d_in[4];
  const float* proj_b  = (const float*)d_in[5];
  const float* dense_w = (const float*)d_in[6];
  const float* dense_b = (const float*)d_in[7];
  const float* fc1_w   = (const float*)d_in[8];
  const float* fc1_b   = (const float*)d_in[9];
  const float* fc2_w   = (const float*)d_in[10];
  const float* fc2_b   = (const float*)d_in[11];
  const float* n1g     = (const float*)d_in[12];
  const float* n1b     = (const float*)d_in[13];
  const float* n2g     = (const float*)d_in[14];
  const float* n2b     = (const float*)d_in[15];

  char*  ws     = (char*)d_ws;
  short* wqkv   = (short*)(ws + 0);
  short* wproj  = (short*)(ws + 245760);
  short* wdense = (short*)(ws + 376832);
  short* wfc1   = (short*)(ws + 458752);
  short* wfc2   = (short*)(ws + 720896);
  bf16*  featB  = (bf16*)(ws + 1048576);
  bf16*  attnA  = (bf16*)(ws + 9437184);
  bf16*  gfmax  = (bf16*)(ws + 17825792);
  int*   idxws  = (int*) (ws + 22282240);
  bf16*  fc1out = (bf16*)(ws + 24379392);

  const int M = Bn * NPn;  // 16384

  knn_kernel<<<dim3(M), dim3(256), 0, stream>>>(xyz, newxyz, idxws);
  wprep_kernel<<<dim3(480), dim3(256), 0, stream>>>(w_qkv,   wqkv,   CGn, 768, 48, 1);
  wprep_kernel<<<dim3(256), dim3(256), 0, stream>>>(proj_w,  wproj,  Cn,  256, 16, 0);
  wprep_kernel<<<dim3(160), dim3(256), 0, stream>>>(dense_w, wdense, CGn, 256, 16, 1);
  wprep_kernel<<<dim3(512), dim3(256), 0, stream>>>(fc1_w,   wfc1,   Cn,  512, 32, 0);
  wprep_kernel<<<dim3(512), dim3(256), 0, stream>>>(fc2_w,   wfc2,   512, 256, 16, 0);

  fused_attn_kernel<<<dim3(M), dim3(256), 0, stream>>>(
      xyz, newxyz, featin, wqkv, n1g, n1b, idxws, attnA, gfmax);
  // featB = relu(attn@proj + pb) + relu(gfmax@dense + db)
  dual_gemm_kernel<<<dim3(2, M/64), dim3(256), 0, stream>>>(
      attnA, wproj, gfmax, wdense, proj_b, dense_b, featB);
  // attnA <- LN2(featB)
  ln2_kernel<<<dim3(M/4), dim3(256), 0, stream>>>(featB, n2g, n2b, attnA);
  // fc1out = relu(attnA @ fc1 + b1)
  mfma_gemm_kernel<true, false, true><<<dim3(4, M/64), dim3(256), 0, stream>>>(
      attnA, Cn, Cn, wfc1, 32, 512, fc1_b, (const bf16*)nullptr, fc1out);
  // out = fc1out @ fc2 + b2 + featB   (fp32 output)
  mfma_gemm_kernel<false, true, false><<<dim3(2, M/64), dim3(256), 0, stream>>>(
      fc1out, 512, 512, wfc2, 16, Cn, fc2_b, featB, d_out);
}

// Round 8
// 836.126 us; speedup vs baseline: 3.2853x; 1.0885x over previous
//
#include <hip/hip_runtime.h>
#include <hip/hip_bf16.h>

typedef __hip_bfloat16 bf16;

#define Bn   16
#define Nn   4096
#define NPn  1024
#define Kn   32
#define CINn 128
#define CGn  131
#define Cn   256
#define Hn   4
#define KPAD 160   // qkv K padded to 5x32 (internal order: feat 0..127, xyz 128..130)
#define XBS  168   // Xb (bf16) row stride (64 rows = 2 points)
#define XFS2 136   // raw-gather (bf16) row stride
#define GFS  136   // gfmax row stride (bf16), pads zeroed

typedef __attribute__((ext_vector_type(8))) short frag_ab;   // 8 bf16
typedef __attribute__((ext_vector_type(4))) float frag_cd;   // 4 fp32

__device__ __forceinline__ float b2f(bf16 x) { return __bfloat162float(x); }
__device__ __forceinline__ bf16  f2b(float x) { return __float2bfloat16(x); }
__device__ __forceinline__ short f2bs(float x) {
  union { bf16 h; short s; } u; u.h = __float2bfloat16(x); return u.s;
}
__device__ __forceinline__ float bs2f(short s) {
  union { short v; bf16 h; } u; u.v = s; return __bfloat162float(u.h);
}
__device__ __forceinline__ unsigned f2ord(float f) {
  unsigned u = __float_as_uint(f);
  return u ^ ((u >> 31) ? 0xffffffffu : 0x80000000u);
}

// =====================================================================
// Kernel 1: KNN, register-cached argmin (unchanged — verified r5-r7).
// =====================================================================
__global__ __launch_bounds__(256) void knn_kernel(const float* __restrict__ xyz,
                                                  const float* __restrict__ newxyz,
                                                  int* __restrict__ idx_out) {
  __shared__ unsigned long long wred[4];
  const int bp  = blockIdx.x;
  const int b   = bp >> 10;
  const int tid = threadIdx.x;
  const float qx = newxyz[bp*3 + 0];
  const float qy = newxyz[bp*3 + 1];
  const float qz = newxyz[bp*3 + 2];
  const float sn = __fadd_rn(__fadd_rn(__fmul_rn(qx,qx), __fmul_rn(qy,qy)),
                             __fmul_rn(qz,qz));
  const float* xb = xyz + (size_t)b * Nn * 3;
  unsigned long long key[16];
  unsigned long long lmin = ~0ull;
  #pragma unroll
  for (int s = 0; s < 16; ++s) {
    const int n = s*256 + tid;
    const float xx = xb[n*3 + 0];
    const float xy = xb[n*3 + 1];
    const float xz = xb[n*3 + 2];
    const float sx  = __fadd_rn(__fadd_rn(__fmul_rn(xx,xx), __fmul_rn(xy,xy)),
                                __fmul_rn(xz,xz));
    const float dot = __fadd_rn(__fadd_rn(__fmul_rn(qx,xx), __fmul_rn(qy,xy)),
                                __fmul_rn(qz,xz));
    const float d2 = __fadd_rn(__fsub_rn(sn, __fmul_rn(2.0f, dot)), sx);
    key[s] = ((unsigned long long)f2ord(d2) << 32) | (unsigned)n;
    if (key[s] < lmin) lmin = key[s];
  }
  const int lane = tid & 63, wv = tid >> 6;
  for (int s = 0; s < Kn; ++s) {
    unsigned long long m = lmin;
    #pragma unroll
    for (int d = 32; d; d >>= 1) {
      const unsigned lo = __shfl_xor((unsigned)(m & 0xffffffffu), d, 64);
      const unsigned hi = __shfl_xor((unsigned)(m >> 32), d, 64);
      const unsigned long long o = ((unsigned long long)hi << 32) | lo;
      if (o < m) m = o;
    }
    if (lane == 0) wred[wv] = m;
    __syncthreads();
    unsigned long long best = wred[0];
    if (wred[1] < best) best = wred[1];
    if (wred[2] < best) best = wred[2];
    if (wred[3] < best) best = wred[3];
    __syncthreads();
    const int n = (int)(best & 0xffffffffu);
    if (tid == 0) idx_out[(size_t)bp*Kn + s] = n;
    if ((n & 255) == tid) {
      const int slot = n >> 8;
      #pragma unroll
      for (int t = 0; t < 16; ++t) if (t == slot) key[t] = ~0ull;
      unsigned long long mm = ~0ull;
      #pragma unroll
      for (int t = 0; t < 16; ++t) if (key[t] < mm) mm = key[t];
      lmin = mm;
    }
  }
}

// =====================================================================
// Kernel 1b: weight pre-swizzle into MFMA B-fragment order (r4-verified).
// remap!=0: internal k-order = [feat(128), xyz(3)].
// =====================================================================
__global__ __launch_bounds__(256) void wprep_kernel(const float* __restrict__ W,
                                                    short* __restrict__ out,
                                                    int K, int N, int nnt, int remap) {
  const int t = blockIdx.x * 256 + threadIdx.x;
  const int j    = t & 7;
  const int lane = (t >> 3) & 63;
  const int nt   = (t >> 9) % nnt;
  const int kt   = (t >> 9) / nnt;
  const int k = kt*32 + (lane >> 4)*8 + j;
  const int n = nt*16 + (lane & 15);
  int krow = k;
  if (remap) krow = (k < 128) ? k + 3 : k - 128;
  out[t] = (k < K) ? f2bs(W[(size_t)krow*N + n]) : (short)0;
}

// =====================================================================
// Kernel 2: fused gather + gf_max + LN1 + MFMA qkv + attention.
// r8: 2 points/block (4 M-tiles/MFMA), 3 sequential Q/K/V passes (64
// live acc regs), register-resident gather + shuffle LN stats, single
// overlaid LDS buffer (raw Xf until gfmax, then Xb). __launch_bounds__
// (256,4) caps VGPRs at 128 -> target 4 blocks/CU.
// =====================================================================
__global__ __launch_bounds__(256, 4) void fused_attn_kernel(
    const float* __restrict__ xyz, const float* __restrict__ newxyz,
    const float* __restrict__ featin, const short* __restrict__ wfrag,
    const float* __restrict__ n1g, const float* __restrict__ n1b,
    const int* __restrict__ idx, bf16* __restrict__ attnout,
    bf16* __restrict__ gfmax) {
  __shared__ __align__(16) short Xs[64 * XBS];   // union: raw (64x136) -> Xb (64x168)
  __shared__ float sg[CGn], sb[CGn];
  __shared__ int sidx[64];
  const int bp0 = blockIdx.x * 2;   // two points, same batch (1024 even)
  const int b   = bp0 >> 10;
  const int tid = threadIdx.x;
  if (tid < 64) {
    int n = idx[(size_t)bp0*Kn + tid];
    sidx[tid] = ((unsigned)n < (unsigned)Nn) ? n : 0;
  }
  if (tid < CGn) {   // LN params, ref->internal: internal j<128 = ref j+3
    const int rj = (tid < 128) ? tid + 3 : tid - 128;
    sg[tid] = n1g[rj];
    sb[tid] = n1b[rj];
  }
  __syncthreads();
  // ---- gather into registers: thread (kk,sub) holds 16 floats per point ----
  const int kk = tid >> 3, sub = tid & 7;
  float4 r[2][4];
  float ex[2] = {0.f, 0.f};
  #pragma unroll
  for (int p = 0; p < 2; ++p) {
    const int row = p*32 + kk;
    const float* frow = featin + ((size_t)b*Nn + sidx[row])*CINn;
    #pragma unroll
    for (int i = 0; i < 4; ++i) r[p][i] = *(const float4*)(frow + sub*4 + 32*i);
    if (sub < 3)
      ex[p] = xyz[((size_t)b*Nn + sidx[row])*3 + sub] - newxyz[(bp0+p)*3 + sub];
  }
  // raw bf16 -> Xs (stride XFS2) for gfmax
  #pragma unroll
  for (int p = 0; p < 2; ++p) {
    const int row = p*32 + kk;
    #pragma unroll
    for (int i = 0; i < 4; ++i) {
      short4 s4 = { f2bs(r[p][i].x), f2bs(r[p][i].y), f2bs(r[p][i].z), f2bs(r[p][i].w) };
      *(short4*)&Xs[row*XFS2 + sub*4 + 32*i] = s4;
    }
    if (sub < 3) Xs[row*XFS2 + 128 + sub] = f2bs(ex[p]);
  }
  // LN stats from raw fp32 registers (8-lane shuffle reduce)
  float mean[2], rstd[2];
  #pragma unroll
  for (int p = 0; p < 2; ++p) {
    float s = ex[p], s2 = ex[p]*ex[p];
    #pragma unroll
    for (int i = 0; i < 4; ++i) {
      s  += r[p][i].x + r[p][i].y + r[p][i].z + r[p][i].w;
      s2 += r[p][i].x*r[p][i].x + r[p][i].y*r[p][i].y
          + r[p][i].z*r[p][i].z + r[p][i].w*r[p][i].w;
    }
    s  += __shfl_xor(s, 1, 64);  s  += __shfl_xor(s, 2, 64);  s  += __shfl_xor(s, 4, 64);
    s2 += __shfl_xor(s2, 1, 64); s2 += __shfl_xor(s2, 2, 64); s2 += __shfl_xor(s2, 4, 64);
    mean[p] = s * (1.0f/CGn);
    const float var = s2 * (1.0f/CGn) - mean[p]*mean[p];
    rstd[p] = rsqrtf(var + 1e-3f);
  }
  __syncthreads();
  // gf_max from raw bf16 (max is monotone under rounding -> bit-exact)
  #pragma unroll
  for (int p = 0; p < 2; ++p) {
    if (tid < GFS) {
      float m = 0.f;
      if (tid < CGn) {
        m = -1e30f;
        #pragma unroll
        for (int k2 = 0; k2 < Kn; ++k2)
          m = fmaxf(m, bs2f(Xs[(p*32 + k2)*XFS2 + tid]));
      }
      gfmax[(size_t)(bp0+p)*GFS + tid] = f2b(m);
    }
  }
  __syncthreads();   // raw buffer dead; overlay Xb
  // normalized bf16 -> Xs (Xb layout, stride XBS) from registers
  #pragma unroll
  for (int p = 0; p < 2; ++p) {
    const int row = p*32 + kk;
    #pragma unroll
    for (int i = 0; i < 4; ++i) {
      const float4 g4 = *(const float4*)&sg[sub*4 + 32*i];
      const float4 b4 = *(const float4*)&sb[sub*4 + 32*i];
      short4 s4;
      s4.x = f2bs((r[p][i].x - mean[p])*rstd[p]*g4.x + b4.x);
      s4.y = f2bs((r[p][i].y - mean[p])*rstd[p]*g4.y + b4.y);
      s4.z = f2bs((r[p][i].z - mean[p])*rstd[p]*g4.z + b4.z);
      s4.w = f2bs((r[p][i].w - mean[p])*rstd[p]*g4.w + b4.w);
      *(short4*)&Xs[row*XBS + sub*4 + 32*i] = s4;
    }
    if (sub < 3)
      Xs[row*XBS + 128 + sub] = f2bs((ex[p] - mean[p])*rstd[p]*sg[128+sub] + sb[128+sub]);
  }
  // zero-pad j in [131,160) for all 64 rows
  #pragma unroll
  for (int u = 0; u < 8; ++u) {
    const int e = u*256 + tid;
    const int row = e >> 5, jj = 131 + (e & 31);
    if (jj < 160) Xs[row*XBS + jj] = 0;
  }
  __syncthreads();
  // ---- MFMA passes: part 0 (Q) -> 1 (K) -> 2 (V); 4 M-tiles = 2 points ----
  const int lane = tid & 63, w = tid >> 6;
  const int col = lane & 15, quad = lane >> 4;
  float qm[2][4], aw[2][2][4], inv[2];
  // pass Q
  {
    frag_cd acc[4][4] = {};   // [ntl][mt]
    for (int kt = 0; kt < 5; ++kt) {
      const int ko = kt*32 + quad*8;
      frag_ab a[4];
      #pragma unroll
      for (int mt = 0; mt < 4; ++mt)
        a[mt] = *(const frag_ab*)&Xs[(mt*16 + col)*XBS + ko];
      #pragma unroll
      for (int ntl = 0; ntl < 4; ++ntl) {
        const int nt = w*4 + ntl;   // part 0
        const frag_ab bfr = *(const frag_ab*)(wfrag + ((size_t)(kt*48 + nt)*64 + lane)*8);
        #pragma unroll
        for (int mt = 0; mt < 4; ++mt)
          acc[ntl][mt] = __builtin_amdgcn_mfma_f32_16x16x32_bf16(a[mt], bfr, acc[ntl][mt], 0, 0, 0);
      }
    }
    #pragma unroll
    for (int p = 0; p < 2; ++p)
      #pragma unroll
      for (int ntl = 0; ntl < 4; ++ntl) {
        float m = -1e30f;
        #pragma unroll
        for (int mtl = 0; mtl < 2; ++mtl)
          #pragma unroll
          for (int rr = 0; rr < 4; ++rr) m = fmaxf(m, acc[ntl][p*2+mtl][rr]);
        m = fmaxf(m, __shfl_xor(m, 16, 64));
        m = fmaxf(m, __shfl_xor(m, 32, 64));
        qm[p][ntl] = m;
      }
  }
  // pass K -> logits -> softmax weights
  {
    frag_cd acc[4][4] = {};
    for (int kt = 0; kt < 5; ++kt) {
      const int ko = kt*32 + quad*8;
      frag_ab a[4];
      #pragma unroll
      for (int mt = 0; mt < 4; ++mt)
        a[mt] = *(const frag_ab*)&Xs[(mt*16 + col)*XBS + ko];
      #pragma unroll
      for (int ntl = 0; ntl < 4; ++ntl) {
        const int nt = 16 + w*4 + ntl;   // part 1
        const frag_ab bfr = *(const frag_ab*)(wfrag + ((size_t)(kt*48 + nt)*64 + lane)*8);
        #pragma unroll
        for (int mt = 0; mt < 4; ++mt)
          acc[ntl][mt] = __builtin_amdgcn_mfma_f32_16x16x32_bf16(a[mt], bfr, acc[ntl][mt], 0, 0, 0);
      }
    }
    #pragma unroll
    for (int p = 0; p < 2; ++p) {
      float lg[2][4];
      #pragma unroll
      for (int mtl = 0; mtl < 2; ++mtl)
        #pragma unroll
        for (int rr = 0; rr < 4; ++rr) {
          float pp = 0.f;
          #pragma unroll
          for (int ntl = 0; ntl < 4; ++ntl) pp = fmaf(qm[p][ntl], acc[ntl][p*2+mtl][rr], pp);
          #pragma unroll
          for (int d = 1; d < 16; d <<= 1) pp += __shfl_xor(pp, d, 64);
          lg[mtl][rr] = pp * 0.0625f;
        }
      float mx = -1e30f;
      #pragma unroll
      for (int mtl = 0; mtl < 2; ++mtl)
        #pragma unroll
        for (int rr = 0; rr < 4; ++rr) mx = fmaxf(mx, lg[mtl][rr]);
      mx = fmaxf(mx, __shfl_xor(mx, 16, 64));
      mx = fmaxf(mx, __shfl_xor(mx, 32, 64));
      float ssum = 0.f;
      #pragma unroll
      for (int mtl = 0; mtl < 2; ++mtl)
        #pragma unroll
        for (int rr = 0; rr < 4; ++rr) { aw[p][mtl][rr] = expf(lg[mtl][rr] - mx); ssum += aw[p][mtl][rr]; }
      ssum += __shfl_xor(ssum, 16, 64);
      ssum += __shfl_xor(ssum, 32, 64);
      inv[p] = 1.f / ssum;
    }
  }
  // pass V -> output
  {
    frag_cd acc[4][4] = {};
    for (int kt = 0; kt < 5; ++kt) {
      const int ko = kt*32 + quad*8;
      frag_ab a[4];
      #pragma unroll
      for (int mt = 0; mt < 4; ++mt)
        a[mt] = *(const frag_ab*)&Xs[(mt*16 + col)*XBS + ko];
      #pragma unroll
      for (int ntl = 0; ntl < 4; ++ntl) {
        const int nt = 32 + w*4 + ntl;   // part 2
        const frag_ab bfr = *(const frag_ab*)(wfrag + ((size_t)(kt*48 + nt)*64 + lane)*8);
        #pragma unroll
        for (int mt = 0; mt < 4; ++mt)
          acc[ntl][mt] = __builtin_amdgcn_mfma_f32_16x16x32_bf16(a[mt], bfr, acc[ntl][mt], 0, 0, 0);
      }
    }
    #pragma unroll
    for (int p = 0; p < 2; ++p)
      #pragma unroll
      for (int ntl = 0; ntl < 4; ++ntl) {
        float o = 0.f;
        #pragma unroll
        for (int mtl = 0; mtl < 2; ++mtl)
          #pragma unroll
          for (int rr = 0; rr < 4; ++rr) o = fmaf(aw[p][mtl][rr], acc[ntl][p*2+mtl][rr], o);
        o += __shfl_xor(o, 16, 64);
        o += __shfl_xor(o, 32, 64);
        if (quad == 0)
          attnout[(size_t)(bp0+p)*Cn + w*64 + ntl*16 + col] = f2b(o * inv[p]);
      }
  }
}

// =====================================================================
// Kernel 3: MFMA GEMM, 64x128 tile (unchanged from r7).
// =====================================================================
template<bool RELU, bool ADD_S, bool OUT_BF16>
__global__ __launch_bounds__(256) void mfma_gemm_kernel(
    const bf16* __restrict__ A, int lda, int Ka,
    const short* __restrict__ Wf, int nnt_total, int N,
    const float* __restrict__ bias, const bf16* __restrict__ S,
    void* __restrict__ Dv) {
  __shared__ __align__(16) short As[64*40];
  const int m0 = blockIdx.y * 64;
  const int n0 = blockIdx.x * 128;
  const int tid = threadIdx.x, lane = tid & 63, w = tid >> 6;
  const int col = lane & 15, quad = lane >> 4;
  const int row = tid >> 2, c8 = (tid & 3) * 8;
  frag_cd acc[4][2] = {};
  const int nkt = (Ka + 31) >> 5;
  for (int kt = 0; kt < nkt; ++kt) {
    const int k0 = kt*32 + c8;
    frag_ab av = {0,0,0,0,0,0,0,0};
    if (k0 + 8 <= Ka)
      av = *(const frag_ab*)((const short*)A + (size_t)(m0+row)*lda + k0);
    __syncthreads();
    *(frag_ab*)&As[row*40 + c8] = av;
    __syncthreads();
    frag_ab afr[4];
    #pragma unroll
    for (int mt = 0; mt < 4; ++mt)
      afr[mt] = *(const frag_ab*)&As[(mt*16 + col)*40 + quad*8];
    #pragma unroll
    for (int ntl = 0; ntl < 2; ++ntl) {
      const int nt = (n0 >> 4) + w*2 + ntl;
      const frag_ab bfr = *(const frag_ab*)(Wf + ((size_t)(kt*nnt_total + nt)*64 + lane)*8);
      #pragma unroll
      for (int mt = 0; mt < 4; ++mt)
        acc[mt][ntl] = __builtin_amdgcn_mfma_f32_16x16x32_bf16(afr[mt], bfr, acc[mt][ntl], 0, 0, 0);
    }
  }
  #pragma unroll
  for (int ntl = 0; ntl < 2; ++ntl) {
    const int n = n0 + w*32 + ntl*16 + col;
    const float bv = bias[n];
    #pragma unroll
    for (int mt = 0; mt < 4; ++mt) {
      #pragma unroll
      for (int r = 0; r < 4; ++r) {
        const int m = m0 + mt*16 + quad*4 + r;
        float v = acc[mt][ntl][r] + bv;
        if (RELU) v = fmaxf(v, 0.f);
        if (ADD_S) v += b2f(S[(size_t)m*N + n]);
        if (OUT_BF16) ((bf16*)Dv)[(size_t)m*N + n] = f2b(v);
        else          ((float*)Dv)[(size_t)m*N + n] = v;
      }
    }
  }
}

// =====================================================================
// Kernel 3b: dual GEMM (proj + dense fused) — unchanged from r7.
// =====================================================================
__global__ __launch_bounds__(256) void dual_gemm_kernel(
    const bf16* __restrict__ A1, const short* __restrict__ W1,
    const bf16* __restrict__ A2, const short* __restrict__ W2,
    const float* __restrict__ b1, const float* __restrict__ b2,
    bf16* __restrict__ D) {
  __shared__ __align__(16) short As[64*40];
  const int m0 = blockIdx.y * 64;
  const int n0 = blockIdx.x * 128;
  const int tid = threadIdx.x, lane = tid & 63, w = tid >> 6;
  const int col = lane & 15, quad = lane >> 4;
  const int row = tid >> 2, c8 = (tid & 3) * 8;
  frag_cd acc1[4][2] = {}, acc2[4][2] = {};
  for (int kt = 0; kt < 8; ++kt) {
    const frag_ab av = *(const frag_ab*)((const short*)A1 + (size_t)(m0+row)*Cn + kt*32 + c8);
    __syncthreads();
    *(frag_ab*)&As[row*40 + c8] = av;
    __syncthreads();
    frag_ab afr[4];
    #pragma unroll
    for (int mt = 0; mt < 4; ++mt)
      afr[mt] = *(const frag_ab*)&As[(mt*16 + col)*40 + quad*8];
    #pragma unroll
    for (int ntl = 0; ntl < 2; ++ntl) {
      const int nt = (n0 >> 4) + w*2 + ntl;
      const frag_ab bfr = *(const frag_ab*)(W1 + ((size_t)(kt*16 + nt)*64 + lane)*8);
      #pragma unroll
      for (int mt = 0; mt < 4; ++mt)
        acc1[mt][ntl] = __builtin_amdgcn_mfma_f32_16x16x32_bf16(afr[mt], bfr, acc1[mt][ntl], 0, 0, 0);
    }
  }
  for (int kt = 0; kt < 5; ++kt) {
    const int k0 = kt*32 + c8;
    frag_ab av = {0,0,0,0,0,0,0,0};
    if (k0 + 8 <= GFS)
      av = *(const frag_ab*)((const short*)A2 + (size_t)(m0+row)*GFS + k0);
    __syncthreads();
    *(frag_ab*)&As[row*40 + c8] = av;
    __syncthreads();
    frag_ab afr[4];
    #pragma unroll
    for (int mt = 0; mt < 4; ++mt)
      afr[mt] = *(const frag_ab*)&As[(mt*16 + col)*40 + quad*8];
    #pragma unroll
    for (int ntl = 0; ntl < 2; ++ntl) {
      const int nt = (n0 >> 4) + w*2 + ntl;
      const frag_ab bfr = *(const frag_ab*)(W2 + ((size_t)(kt*16 + nt)*64 + lane)*8);
      #pragma unroll
      for (int mt = 0; mt < 4; ++mt)
        acc2[mt][ntl] = __builtin_amdgcn_mfma_f32_16x16x32_bf16(afr[mt], bfr, acc2[mt][ntl], 0, 0, 0);
    }
  }
  #pragma unroll
  for (int ntl = 0; ntl < 2; ++ntl) {
    const int n = n0 + w*32 + ntl*16 + col;
    const float bv1 = b1[n], bv2 = b2[n];
    #pragma unroll
    for (int mt = 0; mt < 4; ++mt) {
      #pragma unroll
      for (int r = 0; r < 4; ++r) {
        const int m = m0 + mt*16 + quad*4 + r;
        const float v = fmaxf(acc1[mt][ntl][r] + bv1, 0.f)
                      + fmaxf(acc2[mt][ntl][r] + bv2, 0.f);
        D[(size_t)m*Cn + n] = f2b(v);
      }
    }
  }
}

// =====================================================================
// Kernel 4: LayerNorm2 over C=256, 4 rows/block — unchanged from r7.
// =====================================================================
__global__ __launch_bounds__(256) void ln2_kernel(const bf16* __restrict__ feat,
                                                  const float* __restrict__ g,
                                                  const float* __restrict__ b,
                                                  bf16* __restrict__ out) {
  const int r = blockIdx.x*4 + (threadIdx.x >> 6), lane = threadIdx.x & 63;
  float vv[4];
  #pragma unroll
  for (int c = 0; c < 4; ++c) vv[c] = b2f(feat[(size_t)r*Cn + lane*4 + c]);
  float s  = vv[0] + vv[1] + vv[2] + vv[3];
  float s2 = vv[0]*vv[0] + vv[1]*vv[1] + vv[2]*vv[2] + vv[3]*vv[3];
  #pragma unroll
  for (int d = 32; d; d >>= 1) { s += __shfl_xor(s, d, 64); s2 += __shfl_xor(s2, d, 64); }
  const float mean = s * (1.f/256.f);
  const float var  = s2 * (1.f/256.f) - mean*mean;
  const float rstd = rsqrtf(var + 1e-3f);
  #pragma unroll
  for (int c = 0; c < 4; ++c) {
    const int cc = lane*4 + c;
    out[(size_t)r*Cn + cc] = f2b((vv[c] - mean)*rstd*g[cc] + b[cc]);
  }
}

// =====================================================================
// kernel_launch — fp32 in/out. Workspace (peak 41.16 MB < 41.94 proven):
//   wqkv@0 245,760 | wproj@245,760 131,072 | wdense@376,832 81,920
//   wfc1@458,752 262,144 | wfc2@720,896 262,144 | pad to 1 MiB
//   featB  bf16 [16384*256] @  1,048,576   8 MiB  residual, live to end
//   attnA  bf16 [16384*256] @  9,437,184   8 MiB  attnout -> ln2out
//   gfmax  bf16 [16384*136] @ 17,825,792   4.46 MiB } dead before fc1
//   idx    int  [16384*32]  @ 22,282,240   2 MiB    } fc1out overlays
//   fc1out bf16 [16384*512] @ 24,379,392  16 MiB  (ends 41,156,608)
// =====================================================================
extern "C" void kernel_launch(void* const* d_in, const int* in_sizes, int n_in,
                              void* d_out, int out_size, void* d_ws, size_t ws_size,
                              hipStream_t stream) {
  const float* xyz     = (const float*)d_in[0];
  const float* newxyz  = (const float*)d_in[1];
  const float* featin  = (const float*)d_in[2];
  const float* w_qkv   = (const float*)d_in[3];
  const float* proj_w  = (const float*)d_in[4];
  const float* proj_b  = (const float*)d_in[5];
  const float* dense_w = (const float*)d_in[6];
  const float* dense_b = (const float*)d_in[7];
  const float* fc1_w   = (const float*)d_in[8];
  const float* fc1_b   = (const float*)d_in[9];
  const float* fc2_w   = (const float*)d_in[10];
  const float* fc2_b   = (const float*)d_in[11];
  const float* n1g     = (const float*)d_in[12];
  const float* n1b     = (const float*)d_in[13];
  const float* n2g     = (const float*)d_in[14];
  const float* n2b     = (const float*)d_in[15];

  char*  ws     = (char*)d_ws;
  short* wqkv   = (short*)(ws + 0);
  short* wproj  = (short*)(ws + 245760);
  short* wdense = (short*)(ws + 376832);
  short* wfc1   = (short*)(ws + 458752);
  short* wfc2   = (short*)(ws + 720896);
  bf16*  featB  = (bf16*)(ws + 1048576);
  bf16*  attnA  = (bf16*)(ws + 9437184);
  bf16*  gfmax  = (bf16*)(ws + 17825792);
  int*   idxws  = (int*) (ws + 22282240);
  bf16*  fc1out = (bf16*)(ws + 24379392);

  const int M = Bn * NPn;  // 16384

  knn_kernel<<<dim3(M), dim3(256), 0, stream>>>(xyz, newxyz, idxws);
  wprep_kernel<<<dim3(480), dim3(256), 0, stream>>>(w_qkv,   wqkv,   CGn, 768, 48, 1);
  wprep_kernel<<<dim3(256), dim3(256), 0, stream>>>(proj_w,  wproj,  Cn,  256, 16, 0);
  wprep_kernel<<<dim3(160), dim3(256), 0, stream>>>(dense_w, wdense, CGn, 256, 16, 1);
  wprep_kernel<<<dim3(512), dim3(256), 0, stream>>>(fc1_w,   wfc1,   Cn,  512, 32, 0);
  wprep_kernel<<<dim3(512), dim3(256), 0, stream>>>(fc2_w,   wfc2,   512, 256, 16, 0);

  fused_attn_kernel<<<dim3(M/2), dim3(256), 0, stream>>>(
      xyz, newxyz, featin, wqkv, n1g, n1b, idxws, attnA, gfmax);
  // featB = relu(attn@proj + pb) + relu(gfmax@dense + db)
  dual_gemm_kernel<<<dim3(2, M/64), dim3(256), 0, stream>>>(
      attnA, wproj, gfmax, wdense, proj_b, dense_b, featB);
  // attnA <- LN2(featB)
  ln2_kernel<<<dim3(M/4), dim3(256), 0, stream>>>(featB, n2g, n2b, attnA);
  // fc1out = relu(attnA @ fc1 + b1)
  mfma_gemm_kernel<true, false, true><<<dim3(4, M/64), dim3(256), 0, stream>>>(
      attnA, Cn, Cn, wfc1, 32, 512, fc1_b, (const bf16*)nullptr, fc1out);
  // out = fc1out @ fc2 + b2 + featB   (fp32 output)
  mfma_gemm_kernel<false, true, false><<<dim3(2, M/64), dim3(256), 0, stream>>>(
      fc1out, 512, 512, wfc2, 16, Cn, fc2_b, featB, d_out);
}

// Round 9
// 723.573 us; speedup vs baseline: 3.7964x; 1.1556x over previous
//
#include <hip/hip_runtime.h>
#include <hip/hip_bf16.h>

typedef __hip_bfloat16 bf16;

#define Bn   16
#define Nn   4096
#define NPn  1024
#define Kn   32
#define CINn 128
#define CGn  131
#define Cn   256
#define Hn   4
#define KPAD 160   // qkv K padded to 5x32 (internal order: feat 0..127, xyz 128..130)
#define XBS  168   // Xb (bf16) row stride (64 rows = 2 points)
#define XFS2 136   // raw-gather (bf16) row stride
#define GFS  136   // gfmax row stride (bf16), pads zeroed

typedef __attribute__((ext_vector_type(8))) short frag_ab;   // 8 bf16
typedef __attribute__((ext_vector_type(4))) float frag_cd;   // 4 fp32

__device__ __forceinline__ float b2f(bf16 x) { return __bfloat162float(x); }
__device__ __forceinline__ bf16  f2b(float x) { return __float2bfloat16(x); }
__device__ __forceinline__ short f2bs(float x) {
  union { bf16 h; short s; } u; u.h = __float2bfloat16(x); return u.s;
}
__device__ __forceinline__ float bs2f(short s) {
  union { short v; bf16 h; } u; u.v = s; return __bfloat162float(u.h);
}
__device__ __forceinline__ unsigned f2ord(float f) {
  unsigned u = __float_as_uint(f);
  return u ^ ((u >> 31) ? 0xffffffffu : 0x80000000u);
}

// =====================================================================
// Kernel 1: KNN, register-cached argmin (unchanged — verified r5-r8).
// =====================================================================
__global__ __launch_bounds__(256) void knn_kernel(const float* __restrict__ xyz,
                                                  const float* __restrict__ newxyz,
                                                  int* __restrict__ idx_out) {
  __shared__ unsigned long long wred[4];
  const int bp  = blockIdx.x;
  const int b   = bp >> 10;
  const int tid = threadIdx.x;
  const float qx = newxyz[bp*3 + 0];
  const float qy = newxyz[bp*3 + 1];
  const float qz = newxyz[bp*3 + 2];
  const float sn = __fadd_rn(__fadd_rn(__fmul_rn(qx,qx), __fmul_rn(qy,qy)),
                             __fmul_rn(qz,qz));
  const float* xb = xyz + (size_t)b * Nn * 3;
  unsigned long long key[16];
  unsigned long long lmin = ~0ull;
  #pragma unroll
  for (int s = 0; s < 16; ++s) {
    const int n = s*256 + tid;
    const float xx = xb[n*3 + 0];
    const float xy = xb[n*3 + 1];
    const float xz = xb[n*3 + 2];
    const float sx  = __fadd_rn(__fadd_rn(__fmul_rn(xx,xx), __fmul_rn(xy,xy)),
                                __fmul_rn(xz,xz));
    const float dot = __fadd_rn(__fadd_rn(__fmul_rn(qx,xx), __fmul_rn(qy,xy)),
                                __fmul_rn(qz,xz));
    const float d2 = __fadd_rn(__fsub_rn(sn, __fmul_rn(2.0f, dot)), sx);
    key[s] = ((unsigned long long)f2ord(d2) << 32) | (unsigned)n;
    if (key[s] < lmin) lmin = key[s];
  }
  const int lane = tid & 63, wv = tid >> 6;
  for (int s = 0; s < Kn; ++s) {
    unsigned long long m = lmin;
    #pragma unroll
    for (int d = 32; d; d >>= 1) {
      const unsigned lo = __shfl_xor((unsigned)(m & 0xffffffffu), d, 64);
      const unsigned hi = __shfl_xor((unsigned)(m >> 32), d, 64);
      const unsigned long long o = ((unsigned long long)hi << 32) | lo;
      if (o < m) m = o;
    }
    if (lane == 0) wred[wv] = m;
    __syncthreads();
    unsigned long long best = wred[0];
    if (wred[1] < best) best = wred[1];
    if (wred[2] < best) best = wred[2];
    if (wred[3] < best) best = wred[3];
    __syncthreads();
    const int n = (int)(best & 0xffffffffu);
    if (tid == 0) idx_out[(size_t)bp*Kn + s] = n;
    if ((n & 255) == tid) {
      const int slot = n >> 8;
      #pragma unroll
      for (int t = 0; t < 16; ++t) if (t == slot) key[t] = ~0ull;
      unsigned long long mm = ~0ull;
      #pragma unroll
      for (int t = 0; t < 16; ++t) if (key[t] < mm) mm = key[t];
      lmin = mm;
    }
  }
}

// =====================================================================
// Kernel 1b: ALL weight pre-swizzles in one launch (segment dispatch).
// B-fragment order (r4-verified); remap!=0: internal k = [feat, xyz].
// Segments (block ranges): [0,480) qkv | [480,736) proj | [736,896) dense
// | [896,1408) fc1 | [1408,1920) fc2.
// =====================================================================
__global__ __launch_bounds__(256) void wprep_all_kernel(
    const float* __restrict__ w_qkv, const float* __restrict__ proj_w,
    const float* __restrict__ dense_w, const float* __restrict__ fc1_w,
    const float* __restrict__ fc2_w, short* __restrict__ o_qkv,
    short* __restrict__ o_proj, short* __restrict__ o_dense,
    short* __restrict__ o_fc1, short* __restrict__ o_fc2) {
  const int blk = blockIdx.x;
  const float* W; short* out; int K, N, nnt, remap, base;
  if      (blk <  480) { W=w_qkv;   out=o_qkv;   K=CGn; N=768; nnt=48; remap=1; base=0;    }
  else if (blk <  736) { W=proj_w;  out=o_proj;  K=Cn;  N=256; nnt=16; remap=0; base=480;  }
  else if (blk <  896) { W=dense_w; out=o_dense; K=CGn; N=256; nnt=16; remap=1; base=736;  }
  else if (blk < 1408) { W=fc1_w;   out=o_fc1;   K=Cn;  N=512; nnt=32; remap=0; base=896;  }
  else                 { W=fc2_w;   out=o_fc2;   K=512; N=256; nnt=16; remap=0; base=1408; }
  const int t = (blk - base) * 256 + threadIdx.x;
  const int j    = t & 7;
  const int lane = (t >> 3) & 63;
  const int nt   = (t >> 9) % nnt;
  const int kt   = (t >> 9) / nnt;
  const int k = kt*32 + (lane >> 4)*8 + j;
  const int n = nt*16 + (lane & 15);
  int krow = k;
  if (remap) krow = (k < 128) ? k + 3 : k - 128;
  out[t] = (k < K) ? f2bs(W[(size_t)krow*N + n]) : (short)0;
}

// =====================================================================
// Kernel 2: fused gather + gf_max + LN1 + MFMA qkv + attention.
// r9: __launch_bounds__(256,3) — the r8 (256,4) cap forced ~180 KB/block
// of scratch spill (FETCH 644 MB / WRITE 815 MB per dispatch). 170-reg
// budget holds the ~130-reg live set spill-free at 3 blocks/CU.
// =====================================================================
__global__ __launch_bounds__(256, 3) void fused_attn_kernel(
    const float* __restrict__ xyz, const float* __restrict__ newxyz,
    const float* __restrict__ featin, const short* __restrict__ wfrag,
    const float* __restrict__ n1g, const float* __restrict__ n1b,
    const int* __restrict__ idx, bf16* __restrict__ attnout,
    bf16* __restrict__ gfmax) {
  __shared__ __align__(16) short Xs[64 * XBS];   // union: raw (64x136) -> Xb (64x168)
  __shared__ float sg[CGn], sb[CGn];
  __shared__ int sidx[64];
  const int bp0 = blockIdx.x * 2;   // two points, same batch (1024 even)
  const int b   = bp0 >> 10;
  const int tid = threadIdx.x;
  if (tid < 64) {
    int n = idx[(size_t)bp0*Kn + tid];
    sidx[tid] = ((unsigned)n < (unsigned)Nn) ? n : 0;
  }
  if (tid < CGn) {   // LN params, ref->internal: internal j<128 = ref j+3
    const int rj = (tid < 128) ? tid + 3 : tid - 128;
    sg[tid] = n1g[rj];
    sb[tid] = n1b[rj];
  }
  __syncthreads();
  // ---- gather into registers: thread (kk,sub) holds 16 floats per point ----
  const int kk = tid >> 3, sub = tid & 7;
  float4 r[2][4];
  float ex[2] = {0.f, 0.f};
  #pragma unroll
  for (int p = 0; p < 2; ++p) {
    const int row = p*32 + kk;
    const float* frow = featin + ((size_t)b*Nn + sidx[row])*CINn;
    #pragma unroll
    for (int i = 0; i < 4; ++i) r[p][i] = *(const float4*)(frow + sub*4 + 32*i);
    if (sub < 3)
      ex[p] = xyz[((size_t)b*Nn + sidx[row])*3 + sub] - newxyz[(bp0+p)*3 + sub];
  }
  // raw bf16 -> Xs (stride XFS2) for gfmax
  #pragma unroll
  for (int p = 0; p < 2; ++p) {
    const int row = p*32 + kk;
    #pragma unroll
    for (int i = 0; i < 4; ++i) {
      short4 s4 = { f2bs(r[p][i].x), f2bs(r[p][i].y), f2bs(r[p][i].z), f2bs(r[p][i].w) };
      *(short4*)&Xs[row*XFS2 + sub*4 + 32*i] = s4;
    }
    if (sub < 3) Xs[row*XFS2 + 128 + sub] = f2bs(ex[p]);
  }
  // LN stats from raw fp32 registers (8-lane shuffle reduce)
  float mean[2], rstd[2];
  #pragma unroll
  for (int p = 0; p < 2; ++p) {
    float s = ex[p], s2 = ex[p]*ex[p];
    #pragma unroll
    for (int i = 0; i < 4; ++i) {
      s  += r[p][i].x + r[p][i].y + r[p][i].z + r[p][i].w;
      s2 += r[p][i].x*r[p][i].x + r[p][i].y*r[p][i].y
          + r[p][i].z*r[p][i].z + r[p][i].w*r[p][i].w;
    }
    s  += __shfl_xor(s, 1, 64);  s  += __shfl_xor(s, 2, 64);  s  += __shfl_xor(s, 4, 64);
    s2 += __shfl_xor(s2, 1, 64); s2 += __shfl_xor(s2, 2, 64); s2 += __shfl_xor(s2, 4, 64);
    mean[p] = s * (1.0f/CGn);
    const float var = s2 * (1.0f/CGn) - mean[p]*mean[p];
    rstd[p] = rsqrtf(var + 1e-3f);
  }
  __syncthreads();
  // gf_max from raw bf16 (max is monotone under rounding -> bit-exact)
  #pragma unroll
  for (int p = 0; p < 2; ++p) {
    if (tid < GFS) {
      float m = 0.f;
      if (tid < CGn) {
        m = -1e30f;
        #pragma unroll
        for (int k2 = 0; k2 < Kn; ++k2)
          m = fmaxf(m, bs2f(Xs[(p*32 + k2)*XFS2 + tid]));
      }
      gfmax[(size_t)(bp0+p)*GFS + tid] = f2b(m);
    }
  }
  __syncthreads();   // raw buffer dead; overlay Xb
  // normalized bf16 -> Xs (Xb layout, stride XBS) from registers
  #pragma unroll
  for (int p = 0; p < 2; ++p) {
    const int row = p*32 + kk;
    #pragma unroll
    for (int i = 0; i < 4; ++i) {
      const float4 g4 = *(const float4*)&sg[sub*4 + 32*i];
      const float4 b4 = *(const float4*)&sb[sub*4 + 32*i];
      short4 s4;
      s4.x = f2bs((r[p][i].x - mean[p])*rstd[p]*g4.x + b4.x);
      s4.y = f2bs((r[p][i].y - mean[p])*rstd[p]*g4.y + b4.y);
      s4.z = f2bs((r[p][i].z - mean[p])*rstd[p]*g4.z + b4.z);
      s4.w = f2bs((r[p][i].w - mean[p])*rstd[p]*g4.w + b4.w);
      *(short4*)&Xs[row*XBS + sub*4 + 32*i] = s4;
    }
    if (sub < 3)
      Xs[row*XBS + 128 + sub] = f2bs((ex[p] - mean[p])*rstd[p]*sg[128+sub] + sb[128+sub]);
  }
  // zero-pad j in [131,160) for all 64 rows
  #pragma unroll
  for (int u = 0; u < 8; ++u) {
    const int e = u*256 + tid;
    const int row = e >> 5, jj = 131 + (e & 31);
    if (jj < 160) Xs[row*XBS + jj] = 0;
  }
  __syncthreads();
  // ---- MFMA passes: part 0 (Q) -> 1 (K) -> 2 (V); 4 M-tiles = 2 points ----
  const int lane = tid & 63, w = tid >> 6;
  const int col = lane & 15, quad = lane >> 4;
  float qm[2][4], aw[2][2][4], inv[2];
  // pass Q
  {
    frag_cd acc[4][4] = {};   // [ntl][mt]
    for (int kt = 0; kt < 5; ++kt) {
      const int ko = kt*32 + quad*8;
      frag_ab a[4];
      #pragma unroll
      for (int mt = 0; mt < 4; ++mt)
        a[mt] = *(const frag_ab*)&Xs[(mt*16 + col)*XBS + ko];
      #pragma unroll
      for (int ntl = 0; ntl < 4; ++ntl) {
        const int nt = w*4 + ntl;   // part 0
        const frag_ab bfr = *(const frag_ab*)(wfrag + ((size_t)(kt*48 + nt)*64 + lane)*8);
        #pragma unroll
        for (int mt = 0; mt < 4; ++mt)
          acc[ntl][mt] = __builtin_amdgcn_mfma_f32_16x16x32_bf16(a[mt], bfr, acc[ntl][mt], 0, 0, 0);
      }
    }
    #pragma unroll
    for (int p = 0; p < 2; ++p)
      #pragma unroll
      for (int ntl = 0; ntl < 4; ++ntl) {
        float m = -1e30f;
        #pragma unroll
        for (int mtl = 0; mtl < 2; ++mtl)
          #pragma unroll
          for (int rr = 0; rr < 4; ++rr) m = fmaxf(m, acc[ntl][p*2+mtl][rr]);
        m = fmaxf(m, __shfl_xor(m, 16, 64));
        m = fmaxf(m, __shfl_xor(m, 32, 64));
        qm[p][ntl] = m;
      }
  }
  // pass K -> logits -> softmax weights
  {
    frag_cd acc[4][4] = {};
    for (int kt = 0; kt < 5; ++kt) {
      const int ko = kt*32 + quad*8;
      frag_ab a[4];
      #pragma unroll
      for (int mt = 0; mt < 4; ++mt)
        a[mt] = *(const frag_ab*)&Xs[(mt*16 + col)*XBS + ko];
      #pragma unroll
      for (int ntl = 0; ntl < 4; ++ntl) {
        const int nt = 16 + w*4 + ntl;   // part 1
        const frag_ab bfr = *(const frag_ab*)(wfrag + ((size_t)(kt*48 + nt)*64 + lane)*8);
        #pragma unroll
        for (int mt = 0; mt < 4; ++mt)
          acc[ntl][mt] = __builtin_amdgcn_mfma_f32_16x16x32_bf16(a[mt], bfr, acc[ntl][mt], 0, 0, 0);
      }
    }
    #pragma unroll
    for (int p = 0; p < 2; ++p) {
      float lg[2][4];
      #pragma unroll
      for (int mtl = 0; mtl < 2; ++mtl)
        #pragma unroll
        for (int rr = 0; rr < 4; ++rr) {
          float pp = 0.f;
          #pragma unroll
          for (int ntl = 0; ntl < 4; ++ntl) pp = fmaf(qm[p][ntl], acc[ntl][p*2+mtl][rr], pp);
          #pragma unroll
          for (int d = 1; d < 16; d <<= 1) pp += __shfl_xor(pp, d, 64);
          lg[mtl][rr] = pp * 0.0625f;
        }
      float mx = -1e30f;
      #pragma unroll
      for (int mtl = 0; mtl < 2; ++mtl)
        #pragma unroll
        for (int rr = 0; rr < 4; ++rr) mx = fmaxf(mx, lg[mtl][rr]);
      mx = fmaxf(mx, __shfl_xor(mx, 16, 64));
      mx = fmaxf(mx, __shfl_xor(mx, 32, 64));
      float ssum = 0.f;
      #pragma unroll
      for (int mtl = 0; mtl < 2; ++mtl)
        #pragma unroll
        for (int rr = 0; rr < 4; ++rr) { aw[p][mtl][rr] = expf(lg[mtl][rr] - mx); ssum += aw[p][mtl][rr]; }
      ssum += __shfl_xor(ssum, 16, 64);
      ssum += __shfl_xor(ssum, 32, 64);
      inv[p] = 1.f / ssum;
    }
  }
  // pass V -> output
  {
    frag_cd acc[4][4] = {};
    for (int kt = 0; kt < 5; ++kt) {
      const int ko = kt*32 + quad*8;
      frag_ab a[4];
      #pragma unroll
      for (int mt = 0; mt < 4; ++mt)
        a[mt] = *(const frag_ab*)&Xs[(mt*16 + col)*XBS + ko];
      #pragma unroll
      for (int ntl = 0; ntl < 4; ++ntl) {
        const int nt = 32 + w*4 + ntl;   // part 2
        const frag_ab bfr = *(const frag_ab*)(wfrag + ((size_t)(kt*48 + nt)*64 + lane)*8);
        #pragma unroll
        for (int mt = 0; mt < 4; ++mt)
          acc[ntl][mt] = __builtin_amdgcn_mfma_f32_16x16x32_bf16(a[mt], bfr, acc[ntl][mt], 0, 0, 0);
      }
    }
    #pragma unroll
    for (int p = 0; p < 2; ++p)
      #pragma unroll
      for (int ntl = 0; ntl < 4; ++ntl) {
        float o = 0.f;
        #pragma unroll
        for (int mtl = 0; mtl < 2; ++mtl)
          #pragma unroll
          for (int rr = 0; rr < 4; ++rr) o = fmaf(aw[p][mtl][rr], acc[ntl][p*2+mtl][rr], o);
        o += __shfl_xor(o, 16, 64);
        o += __shfl_xor(o, 32, 64);
        if (quad == 0)
          attnout[(size_t)(bp0+p)*Cn + w*64 + ntl*16 + col] = f2b(o * inv[p]);
      }
  }
}

// =====================================================================
// Kernel 3: MFMA GEMM, 64x128 tile (unchanged from r7/r8).
// =====================================================================
template<bool RELU, bool ADD_S, bool OUT_BF16>
__global__ __launch_bounds__(256) void mfma_gemm_kernel(
    const bf16* __restrict__ A, int lda, int Ka,
    const short* __restrict__ Wf, int nnt_total, int N,
    const float* __restrict__ bias, const bf16* __restrict__ S,
    void* __restrict__ Dv) {
  __shared__ __align__(16) short As[64*40];
  const int m0 = blockIdx.y * 64;
  const int n0 = blockIdx.x * 128;
  const int tid = threadIdx.x, lane = tid & 63, w = tid >> 6;
  const int col = lane & 15, quad = lane >> 4;
  const int row = tid >> 2, c8 = (tid & 3) * 8;
  frag_cd acc[4][2] = {};
  const int nkt = (Ka + 31) >> 5;
  for (int kt = 0; kt < nkt; ++kt) {
    const int k0 = kt*32 + c8;
    frag_ab av = {0,0,0,0,0,0,0,0};
    if (k0 + 8 <= Ka)
      av = *(const frag_ab*)((const short*)A + (size_t)(m0+row)*lda + k0);
    __syncthreads();
    *(frag_ab*)&As[row*40 + c8] = av;
    __syncthreads();
    frag_ab afr[4];
    #pragma unroll
    for (int mt = 0; mt < 4; ++mt)
      afr[mt] = *(const frag_ab*)&As[(mt*16 + col)*40 + quad*8];
    #pragma unroll
    for (int ntl = 0; ntl < 2; ++ntl) {
      const int nt = (n0 >> 4) + w*2 + ntl;
      const frag_ab bfr = *(const frag_ab*)(Wf + ((size_t)(kt*nnt_total + nt)*64 + lane)*8);
      #pragma unroll
      for (int mt = 0; mt < 4; ++mt)
        acc[mt][ntl] = __builtin_amdgcn_mfma_f32_16x16x32_bf16(afr[mt], bfr, acc[mt][ntl], 0, 0, 0);
    }
  }
  #pragma unroll
  for (int ntl = 0; ntl < 2; ++ntl) {
    const int n = n0 + w*32 + ntl*16 + col;
    const float bv = bias[n];
    #pragma unroll
    for (int mt = 0; mt < 4; ++mt) {
      #pragma unroll
      for (int r = 0; r < 4; ++r) {
        const int m = m0 + mt*16 + quad*4 + r;
        float v = acc[mt][ntl][r] + bv;
        if (RELU) v = fmaxf(v, 0.f);
        if (ADD_S) v += b2f(S[(size_t)m*N + n]);
        if (OUT_BF16) ((bf16*)Dv)[(size_t)m*N + n] = f2b(v);
        else          ((float*)Dv)[(size_t)m*N + n] = v;
      }
    }
  }
}

// =====================================================================
// Kernel 3b: dual GEMM (proj + dense fused) — unchanged from r7/r8.
// =====================================================================
__global__ __launch_bounds__(256) void dual_gemm_kernel(
    const bf16* __restrict__ A1, const short* __restrict__ W1,
    const bf16* __restrict__ A2, const short* __restrict__ W2,
    const float* __restrict__ b1, const float* __restrict__ b2,
    bf16* __restrict__ D) {
  __shared__ __align__(16) short As[64*40];
  const int m0 = blockIdx.y * 64;
  const int n0 = blockIdx.x * 128;
  const int tid = threadIdx.x, lane = tid & 63, w = tid >> 6;
  const int col = lane & 15, quad = lane >> 4;
  const int row = tid >> 2, c8 = (tid & 3) * 8;
  frag_cd acc1[4][2] = {}, acc2[4][2] = {};
  for (int kt = 0; kt < 8; ++kt) {
    const frag_ab av = *(const frag_ab*)((const short*)A1 + (size_t)(m0+row)*Cn + kt*32 + c8);
    __syncthreads();
    *(frag_ab*)&As[row*40 + c8] = av;
    __syncthreads();
    frag_ab afr[4];
    #pragma unroll
    for (int mt = 0; mt < 4; ++mt)
      afr[mt] = *(const frag_ab*)&As[(mt*16 + col)*40 + quad*8];
    #pragma unroll
    for (int ntl = 0; ntl < 2; ++ntl) {
      const int nt = (n0 >> 4) + w*2 + ntl;
      const frag_ab bfr = *(const frag_ab*)(W1 + ((size_t)(kt*16 + nt)*64 + lane)*8);
      #pragma unroll
      for (int mt = 0; mt < 4; ++mt)
        acc1[mt][ntl] = __builtin_amdgcn_mfma_f32_16x16x32_bf16(afr[mt], bfr, acc1[mt][ntl], 0, 0, 0);
    }
  }
  for (int kt = 0; kt < 5; ++kt) {
    const int k0 = kt*32 + c8;
    frag_ab av = {0,0,0,0,0,0,0,0};
    if (k0 + 8 <= GFS)
      av = *(const frag_ab*)((const short*)A2 + (size_t)(m0+row)*GFS + k0);
    __syncthreads();
    *(frag_ab*)&As[row*40 + c8] = av;
    __syncthreads();
    frag_ab afr[4];
    #pragma unroll
    for (int mt = 0; mt < 4; ++mt)
      afr[mt] = *(const frag_ab*)&As[(mt*16 + col)*40 + quad*8];
    #pragma unroll
    for (int ntl = 0; ntl < 2; ++ntl) {
      const int nt = (n0 >> 4) + w*2 + ntl;
      const frag_ab bfr = *(const frag_ab*)(W2 + ((size_t)(kt*16 + nt)*64 + lane)*8);
      #pragma unroll
      for (int mt = 0; mt < 4; ++mt)
        acc2[mt][ntl] = __builtin_amdgcn_mfma_f32_16x16x32_bf16(afr[mt], bfr, acc2[mt][ntl], 0, 0, 0);
    }
  }
  #pragma unroll
  for (int ntl = 0; ntl < 2; ++ntl) {
    const int n = n0 + w*32 + ntl*16 + col;
    const float bv1 = b1[n], bv2 = b2[n];
    #pragma unroll
    for (int mt = 0; mt < 4; ++mt) {
      #pragma unroll
      for (int r = 0; r < 4; ++r) {
        const int m = m0 + mt*16 + quad*4 + r;
        const float v = fmaxf(acc1[mt][ntl][r] + bv1, 0.f)
                      + fmaxf(acc2[mt][ntl][r] + bv2, 0.f);
        D[(size_t)m*Cn + n] = f2b(v);
      }
    }
  }
}

// =====================================================================
// Kernel 4: LayerNorm2 over C=256, 4 rows/block — unchanged.
// =====================================================================
__global__ __launch_bounds__(256) void ln2_kernel(const bf16* __restrict__ feat,
                                                  const float* __restrict__ g,
                                                  const float* __restrict__ b,
                                                  bf16* __restrict__ out) {
  const int r = blockIdx.x*4 + (threadIdx.x >> 6), lane = threadIdx.x & 63;
  float vv[4];
  #pragma unroll
  for (int c = 0; c < 4; ++c) vv[c] = b2f(feat[(size_t)r*Cn + lane*4 + c]);
  float s  = vv[0] + vv[1] + vv[2] + vv[3];
  float s2 = vv[0]*vv[0] + vv[1]*vv[1] + vv[2]*vv[2] + vv[3]*vv[3];
  #pragma unroll
  for (int d = 32; d; d >>= 1) { s += __shfl_xor(s, d, 64); s2 += __shfl_xor(s2, d, 64); }
  const float mean = s * (1.f/256.f);
  const float var  = s2 * (1.f/256.f) - mean*mean;
  const float rstd = rsqrtf(var + 1e-3f);
  #pragma unroll
  for (int c = 0; c < 4; ++c) {
    const int cc = lane*4 + c;
    out[(size_t)r*Cn + cc] = f2b((vv[c] - mean)*rstd*g[cc] + b[cc]);
  }
}

// =====================================================================
// kernel_launch — fp32 in/out. Workspace (peak 41.16 MB < 41.94 proven):
//   wqkv@0 245,760 | wproj@245,760 131,072 | wdense@376,832 81,920
//   wfc1@458,752 262,144 | wfc2@720,896 262,144 | pad to 1 MiB
//   featB  bf16 [16384*256] @  1,048,576   8 MiB  residual, live to end
//   attnA  bf16 [16384*256] @  9,437,184   8 MiB  attnout -> ln2out
//   gfmax  bf16 [16384*136] @ 17,825,792   4.46 MiB } dead before fc1
//   idx    int  [16384*32]  @ 22,282,240   2 MiB    } fc1out overlays
//   fc1out bf16 [16384*512] @ 24,379,392  16 MiB  (ends 41,156,608)
// =====================================================================
extern "C" void kernel_launch(void* const* d_in, const int* in_sizes, int n_in,
                              void* d_out, int out_size, void* d_ws, size_t ws_size,
                              hipStream_t stream) {
  const float* xyz     = (const float*)d_in[0];
  const float* newxyz  = (const float*)d_in[1];
  const float* featin  = (const float*)d_in[2];
  const float* w_qkv   = (const float*)d_in[3];
  const float* proj_w  = (const float*)d_in[4];
  const float* proj_b  = (const float*)d_in[5];
  const float* dense_w = (const float*)d_in[6];
  const float* dense_b = (const float*)d_in[7];
  const float* fc1_w   = (const float*)d_in[8];
  const float* fc1_b   = (const float*)d_in[9];
  const float* fc2_w   = (const float*)d_in[10];
  const float* fc2_b   = (const float*)d_in[11];
  const float* n1g     = (const float*)d_in[12];
  const float* n1b     = (const float*)d_in[13];
  const float* n2g     = (const float*)d_in[14];
  const float* n2b     = (const float*)d_in[15];

  char*  ws     = (char*)d_ws;
  short* wqkv   = (short*)(ws + 0);
  short* wproj  = (short*)(ws + 245760);
  short* wdense = (short*)(ws + 376832);
  short* wfc1   = (short*)(ws + 458752);
  short* wfc2   = (short*)(ws + 720896);
  bf16*  featB  = (bf16*)(ws + 1048576);
  bf16*  attnA  = (bf16*)(ws + 9437184);
  bf16*  gfmax  = (bf16*)(ws + 17825792);
  int*   idxws  = (int*) (ws + 22282240);
  bf16*  fc1out = (bf16*)(ws + 24379392);

  const int M = Bn * NPn;  // 16384

  knn_kernel<<<dim3(M), dim3(256), 0, stream>>>(xyz, newxyz, idxws);
  wprep_all_kernel<<<dim3(1920), dim3(256), 0, stream>>>(
      w_qkv, proj_w, dense_w, fc1_w, fc2_w, wqkv, wproj, wdense, wfc1, wfc2);

  fused_attn_kernel<<<dim3(M/2), dim3(256), 0, stream>>>(
      xyz, newxyz, featin, wqkv, n1g, n1b, idxws, attnA, gfmax);
  // featB = relu(attn@proj + pb) + relu(gfmax@dense + db)
  dual_gemm_kernel<<<dim3(2, M/64), dim3(256), 0, stream>>>(
      attnA, wproj, gfmax, wdense, proj_b, dense_b, featB);
  // attnA <- LN2(featB)
  ln2_kernel<<<dim3(M/4), dim3(256), 0, stream>>>(featB, n2g, n2b, attnA);
  // fc1out = relu(attnA @ fc1 + b1)
  mfma_gemm_kernel<true, false, true><<<dim3(4, M/64), dim3(256), 0, stream>>>(
      attnA, Cn, Cn, wfc1, 32, 512, fc1_b, (const bf16*)nullptr, fc1out);
  // out = fc1out @ fc2 + b2 + featB   (fp32 output)
  mfma_gemm_kernel<false, true, false><<<dim3(2, M/64), dim3(256), 0, stream>>>(
      fc1out, 512, 512, wfc2, 16, Cn, fc2_b, featB, d_out);
}